// Round 3
// baseline (4470.000 us; speedup 1.0000x reference)
//
#include <hip/hip_runtime.h>
#include <cstddef>

#define DEV __device__ __forceinline__
#define AGENT __HIP_MEMORY_SCOPE_AGENT

DEV float fexp2(float x) { return __builtin_amdgcn_exp2f(x); }
DEV float frcp(float x)  { return __builtin_amdgcn_rcpf(x); }
DEV float fsigm(float x) { return frcp(1.0f + fexp2(-1.44269504f * x)); }
DEV float ftanh_(float x){ return 1.0f - 2.0f * frcp(1.0f + fexp2(2.88539008f * x)); }

typedef _Float16 h2t __attribute__((ext_vector_type(2)));
union U32H2 { unsigned int u; h2t h; };
DEV h2t u2h(unsigned int u) { U32H2 x; x.u = u; return x.h; }

// ---------------------------------------------------------------------------
// Generic fp32 GEMM: C[M,N] = A[M,K] @ W[N,K]^T + bias1 (+bias2), optional relu
// ---------------------------------------------------------------------------
template <int BN, bool RELU>
__global__ __launch_bounds__(256) void gemm_kernel(
    const float* __restrict__ A, const float* __restrict__ W,
    const float* __restrict__ bias1, const float* __restrict__ bias2,
    float* __restrict__ C, int M, int N, int K)
{
    constexpr int BM = 128, BK = 16;
    constexpr int NC = BN / 64;
    __shared__ float As[BK][BM + 4];
    __shared__ float Bs[BK][BN + 4];

    const int tid = threadIdx.x;
    const int tx = tid & 15, ty = tid >> 4;
    const int m0 = blockIdx.x * BM, n0 = blockIdx.y * BN;

    float acc[2][NC][4][4];
#pragma unroll
    for (int rh = 0; rh < 2; ++rh)
#pragma unroll
        for (int ch = 0; ch < NC; ++ch)
#pragma unroll
            for (int i = 0; i < 4; ++i)
#pragma unroll
                for (int j = 0; j < 4; ++j) acc[rh][ch][i][j] = 0.f;

    for (int k0 = 0; k0 < K; k0 += BK) {
#pragma unroll
        for (int l = 0; l < 2; ++l) {
            int idx = tid + l * 256;
            int row = idx >> 2, kc4 = idx & 3;
            float4 v = *(const float4*)&A[(size_t)(m0 + row) * K + k0 + kc4 * 4];
            As[kc4 * 4 + 0][row] = v.x; As[kc4 * 4 + 1][row] = v.y;
            As[kc4 * 4 + 2][row] = v.z; As[kc4 * 4 + 3][row] = v.w;
        }
#pragma unroll
        for (int l = 0; l < BN / 64; ++l) {
            int idx = tid + l * 256;
            int row = idx >> 2, kc4 = idx & 3;
            float4 v = *(const float4*)&W[(size_t)(n0 + row) * K + k0 + kc4 * 4];
            Bs[kc4 * 4 + 0][row] = v.x; Bs[kc4 * 4 + 1][row] = v.y;
            Bs[kc4 * 4 + 2][row] = v.z; Bs[kc4 * 4 + 3][row] = v.w;
        }
        __syncthreads();
#pragma unroll
        for (int kk = 0; kk < BK; ++kk) {
            const float4 a0 = *(const float4*)&As[kk][ty * 4];
            const float4 a1 = *(const float4*)&As[kk][64 + ty * 4];
            float ar[2][4] = {{a0.x, a0.y, a0.z, a0.w}, {a1.x, a1.y, a1.z, a1.w}};
            float br[NC][4];
            const float4 b0 = *(const float4*)&Bs[kk][tx * 4];
            br[0][0] = b0.x; br[0][1] = b0.y; br[0][2] = b0.z; br[0][3] = b0.w;
            if (NC == 2) {
                const float4 b1 = *(const float4*)&Bs[kk][64 + tx * 4];
                br[1][0] = b1.x; br[1][1] = b1.y; br[1][2] = b1.z; br[1][3] = b1.w;
            }
#pragma unroll
            for (int rh = 0; rh < 2; ++rh)
#pragma unroll
                for (int ch = 0; ch < NC; ++ch)
#pragma unroll
                    for (int i = 0; i < 4; ++i)
#pragma unroll
                        for (int j = 0; j < 4; ++j)
                            acc[rh][ch][i][j] += ar[rh][i] * br[ch][j];
        }
        __syncthreads();
    }

#pragma unroll
    for (int ch = 0; ch < NC; ++ch) {
        int col = n0 + ch * 64 + tx * 4;
        float4 bv = *(const float4*)&bias1[col];
        if (bias2) {
            float4 b2 = *(const float4*)&bias2[col];
            bv.x += b2.x; bv.y += b2.y; bv.z += b2.z; bv.w += b2.w;
        }
#pragma unroll
        for (int rh = 0; rh < 2; ++rh)
#pragma unroll
            for (int i = 0; i < 4; ++i) {
                int row = m0 + rh * 64 + ty * 4 + i;
                float4 r;
                r.x = acc[rh][ch][i][0] + bv.x;
                r.y = acc[rh][ch][i][1] + bv.y;
                r.z = acc[rh][ch][i][2] + bv.z;
                r.w = acc[rh][ch][i][3] + bv.w;
                if (RELU) {
                    r.x = fmaxf(r.x, 0.f); r.y = fmaxf(r.y, 0.f);
                    r.z = fmaxf(r.z, 0.f); r.w = fmaxf(r.w, 0.f);
                }
                *(float4*)&C[(size_t)row * N + col] = r;
            }
    }
}

// ---------------------------------------------------------------------------
__global__ __launch_bounds__(64) void bin_enc_kernel(
    const float* __restrict__ bin_info, const float* __restrict__ W1,
    const float* __restrict__ b1, const float* __restrict__ W2,
    const float* __restrict__ b2, float* __restrict__ BBo)
{
    int b = blockIdx.x, d = threadIdx.x;
    __shared__ float h1[64];
    float x0 = bin_info[b * 2], x1 = bin_info[b * 2 + 1];
    h1[d] = fmaxf(W1[d * 2] * x0 + W1[d * 2 + 1] * x1 + b1[d], 0.f);
    __syncthreads();
    float acc = b2[d];
#pragma unroll 4
    for (int e = 0; e < 64; ++e) acc += W2[d * 64 + e] * h1[e];
    BBo[b * 64 + d] = acc;
}

// ---------------------------------------------------------------------------
__global__ __launch_bounds__(128) void part_enc_kernel(
    const float* __restrict__ parts, const float* __restrict__ W1,
    const float* __restrict__ b1, const float* __restrict__ W2,
    const float* __restrict__ b2, const float* __restrict__ BBi,
    const float* __restrict__ pos_emb, float* __restrict__ X)
{
    __shared__ float W2s[128][129];
    __shared__ float h1[128];
    __shared__ float pin[16];
    int tid = threadIdx.x;
    int b = blockIdx.x >> 3, s0 = (blockIdx.x & 7) * 32;
    for (int l = 0; l < 128; ++l) W2s[l][tid] = W2[l * 128 + tid];
    float w1r[16];
#pragma unroll
    for (int k = 0; k < 16; ++k) w1r[k] = W1[tid * 16 + k];
    float bias1v = b1[tid], bias2v = b2[tid];
    for (int si = 0; si < 32; ++si) {
        int s = s0 + si;
        size_t row = (size_t)b * 256 + s;
        if (tid < 16) pin[tid] = parts[row * 16 + tid];
        __syncthreads();
        float h = bias1v;
#pragma unroll
        for (int k = 0; k < 16; ++k) h += w1r[k] * pin[k];
        h1[tid] = fmaxf(h, 0.f);
        __syncthreads();
        float acc = bias2v;
#pragma unroll 4
        for (int e = 0; e < 128; ++e) acc += W2s[tid][e] * h1[e];
        X[row * 256 + tid] = acc;
        if (tid < 64) {
            X[row * 256 + 128 + tid] = BBi[b * 64 + tid];
            X[row * 256 + 192 + tid] = pos_emb[s * 64 + tid];
        }
        __syncthreads();
    }
}

// ---------------------------------------------------------------------------
__global__ __launch_bounds__(256) void attn_kernel(
    const float* __restrict__ QKV, float* __restrict__ O)
{
    int bh = blockIdx.x;
    int b = bh >> 3, h = bh & 7;
    int s = threadIdx.x;
    __shared__ float k_s[256][36];
    __shared__ float v_s[256][36];
    const float scale = 0.17677669529663687f;
    const float c_log2e = 1.44269504f;

    const float* base = QKV + ((size_t)(b * 256 + s)) * 768 + h * 32;
    float q[32];
#pragma unroll
    for (int d4 = 0; d4 < 8; ++d4) {
        float4 qv = *(const float4*)(base + d4 * 4);
        q[d4 * 4 + 0] = qv.x; q[d4 * 4 + 1] = qv.y;
        q[d4 * 4 + 2] = qv.z; q[d4 * 4 + 3] = qv.w;
        float4 kv = *(const float4*)(base + 256 + d4 * 4);
        *(float4*)&k_s[s][d4 * 4] = kv;
        float4 vv = *(const float4*)(base + 512 + d4 * 4);
        *(float4*)&v_s[s][d4 * 4] = vv;
    }
    __syncthreads();

    float mmax = -1e30f;
    for (int j = 0; j < 256; ++j) {
        float sc = 0.f;
#pragma unroll
        for (int d4 = 0; d4 < 8; ++d4) {
            float4 kv = *(const float4*)&k_s[j][d4 * 4];
            sc += q[d4 * 4 + 0] * kv.x + q[d4 * 4 + 1] * kv.y
                + q[d4 * 4 + 2] * kv.z + q[d4 * 4 + 3] * kv.w;
        }
        mmax = fmaxf(mmax, sc);
    }
    float sum = 0.f;
    float o[32];
#pragma unroll
    for (int d = 0; d < 32; ++d) o[d] = 0.f;
    for (int j = 0; j < 256; ++j) {
        float sc = 0.f;
#pragma unroll
        for (int d4 = 0; d4 < 8; ++d4) {
            float4 kv = *(const float4*)&k_s[j][d4 * 4];
            sc += q[d4 * 4 + 0] * kv.x + q[d4 * 4 + 1] * kv.y
                + q[d4 * 4 + 2] * kv.z + q[d4 * 4 + 3] * kv.w;
        }
        float e = fexp2((sc - mmax) * (scale * c_log2e));
        sum += e;
#pragma unroll
        for (int d4 = 0; d4 < 8; ++d4) {
            float4 vv = *(const float4*)&v_s[j][d4 * 4];
            o[d4 * 4 + 0] += e * vv.x; o[d4 * 4 + 1] += e * vv.y;
            o[d4 * 4 + 2] += e * vv.z; o[d4 * 4 + 3] += e * vv.w;
        }
    }
    float inv = 1.0f / sum;
    float* op = O + ((size_t)(b * 256 + s)) * 256 + h * 32;
#pragma unroll
    for (int d4 = 0; d4 < 8; ++d4) {
        float4 r;
        r.x = o[d4 * 4 + 0] * inv; r.y = o[d4 * 4 + 1] * inv;
        r.z = o[d4 * 4 + 2] * inv; r.w = o[d4 * 4 + 3] * inv;
        *(float4*)(op + d4 * 4) = r;
    }
}

// ---------------------------------------------------------------------------
__global__ __launch_bounds__(256) void add_ln_kernel(
    float* __restrict__ X, const float* __restrict__ R,
    const float* __restrict__ g, const float* __restrict__ beta)
{
    size_t row = blockIdx.x;
    int d = threadIdx.x;
    float y = X[row * 256 + d] + R[row * 256 + d];
    float s = y, s2 = y * y;
#pragma unroll
    for (int o = 32; o; o >>= 1) {
        s += __shfl_down(s, o);
        s2 += __shfl_down(s2, o);
    }
    __shared__ float red[8];
    int wid = d >> 6, lane = d & 63;
    if (lane == 0) { red[wid] = s; red[4 + wid] = s2; }
    __syncthreads();
    if (d == 0) {
        float a = 0.f, b2 = 0.f;
        for (int w = 0; w < 4; ++w) { a += red[w]; b2 += red[4 + w]; }
        red[0] = a * (1.f / 256.f);
        red[1] = b2 * (1.f / 256.f);
    }
    __syncthreads();
    float m = red[0];
    float var = red[1] - m * m;
    float inv = rsqrtf(var + 1e-5f);
    X[row * 256 + d] = (y - m) * inv * g[d] + beta[d];
}

// ---------------------------------------------------------------------------
__global__ __launch_bounds__(256) void gather_kernel(
    const float* __restrict__ X, const int* __restrict__ target,
    float* __restrict__ Xg)
{
    int row = blockIdx.x;
    int b = row >> 8, t = row & 255;
    int d = threadIdx.x;
    float val = 0.f;
    if (t > 0) {
        int src = target[b * 256 + t - 1];
        val = X[((size_t)b * 256 + src) * 256 + d];
    }
    Xg[(size_t)row * 256 + d] = val;
}

// ---------------------------------------------------------------------------
// Whh fp32 [1024,256] -> per-q-block f16 packed layout:
// WQ[((q*32 + k8)*256 + r)*4 + u] = half2( W[J][8k8+2u], W[J][8k8+2u+1] )
// where J = (r>>6)*256 + q*64 + (r&63).
// ---------------------------------------------------------------------------
__global__ __launch_bounds__(256) void wcvt_f16_kernel(
    const float* __restrict__ Whh, unsigned int* __restrict__ WQ)
{
    int o = blockIdx.x * 256 + threadIdx.x;   // 0..131071
    int u = o & 3, r = (o >> 2) & 255, k8 = (o >> 10) & 31, q = o >> 15;
    int J = ((r >> 6) << 8) + (q << 6) + (r & 63);
    int k = (k8 << 3) + (u << 1);
    _Float16 lo = (_Float16)Whh[J * 256 + k];
    _Float16 hi = (_Float16)Whh[J * 256 + k + 1];
    U32H2 x; x.h = h2t{lo, hi};
    WQ[o] = x.u;
}

__global__ __launch_bounds__(256) void clear_flags_kernel(int* __restrict__ f)
{
    f[blockIdx.x * 256 + threadIdx.x] = 0;
}

// ---------------------------------------------------------------------------
// LSTM recurrence, 4 blocks per batch (grid 128, b=blk&31 so a batch's blocks
// share an XCD). Block q owns cells [64q,64q+64) — all 4 gates — with its
// 256x256 f16 weight slice resident in LDS. Per step: LDS matvec via
// v_dot2_f32_f16, wave0 updates c/h, h-slice published via agent-scope
// release store + flag; consumers acquire-poll flag[t-1] (monotonic, no ABA).
// ---------------------------------------------------------------------------
__global__ __launch_bounds__(256) void lstm_kernel(
    const float* __restrict__ g_in, const unsigned int* __restrict__ WQ,
    float* __restrict__ HALL, unsigned int* __restrict__ H2,
    int* __restrict__ flags)
{
    const int blk = blockIdx.x;
    const int b = blk & 31, q = blk >> 5;
    const int tid = threadIdx.x;

    __shared__ unsigned int wlds[32768];   // 128 KB
    __shared__ unsigned int h2_s[128];
    __shared__ float gv_s[256];

    // one-time weight load (128 KB from L2/HBM)
    {
        const uint4* ws4 = (const uint4*)(WQ + (size_t)q * 32768);
        uint4* wl4 = (uint4*)wlds;
        for (int i = tid; i < 8192; i += 256) wl4[i] = ws4[i];
    }
    __syncthreads();

    const int g = tid >> 6, jloc = tid & 63;
    const int J = (g << 8) + (q << 6) + jloc;
    const size_t gbase = (size_t)b * 256 * 1024 + J;
    int* flagb = flags + b * 256;
    unsigned int* h2b = H2 + (size_t)b * 256 * 128;
    float c = 0.f;

    for (int t = 0; t < 256; ++t) {
        float gval = g_in[gbase + (size_t)t * 1024];  // issued early, used late
        float acc = 0.f;
        if (t > 0) {
            // wait for all 4 slices of h_{t-1}
            while (__hip_atomic_load(&flagb[t - 1], __ATOMIC_ACQUIRE, AGENT) != 4)
                __builtin_amdgcn_s_sleep(2);
            const unsigned int* src = h2b + (size_t)(t - 1) * 128;
            if (tid < 128) h2_s[tid] = src[tid];
            __syncthreads();
            const uint4* wl4 = (const uint4*)wlds;
            const uint4* h4 = (const uint4*)h2_s;
#pragma unroll 8
            for (int k8 = 0; k8 < 32; ++k8) {
                uint4 w = wl4[k8 * 256 + tid];
                uint4 hh = h4[k8];
                acc = __builtin_amdgcn_fdot2(u2h(w.x), u2h(hh.x), acc, false);
                acc = __builtin_amdgcn_fdot2(u2h(w.y), u2h(hh.y), acc, false);
                acc = __builtin_amdgcn_fdot2(u2h(w.z), u2h(hh.z), acc, false);
                acc = __builtin_amdgcn_fdot2(u2h(w.w), u2h(hh.w), acc, false);
            }
        }
        gv_s[tid] = gval + acc;
        __syncthreads();
        if (tid < 64) {
            float ig = gv_s[tid], fg = gv_s[64 + tid];
            float gg = gv_s[128 + tid], og = gv_s[192 + tid];
            c = fsigm(fg) * c + fsigm(ig) * ftanh_(gg);
            float h = fsigm(og) * ftanh_(c);
            HALL[((size_t)(b * 256 + t)) * 256 + (q << 6) + tid] = h;
            U32H2 hx; hx.h = h2t{(_Float16)h, (_Float16)0.f};
            unsigned int hu = hx.u & 0xffffu;
            unsigned int other = (unsigned int)__shfl_xor((int)hu, 1);
            if ((tid & 1) == 0)
                h2b[(size_t)t * 128 + (q << 5) + (tid >> 1)] = hu | (other << 16);
        }
        __syncthreads();
        if (tid == 0) {
            __threadfence();  // agent-scope release of HALL/H2 stores (wave 0)
            __hip_atomic_fetch_add(&flagb[t], 1, __ATOMIC_RELEASE, AGENT);
        }
        // next iteration's h2_s overwrite is gated by the t>0 spin + barrier
    }
}

// ---------------------------------------------------------------------------
__global__ __launch_bounds__(256) void pointer_kernel(
    const float* __restrict__ HP, const float* __restrict__ EP,
    const float* __restrict__ v, float* __restrict__ out)
{
    int b = blockIdx.z, tt = blockIdx.y, it = blockIdx.x;
    __shared__ float hp_s[16][260];
    __shared__ float ep_s[16][260];
    __shared__ float v_s[256];
    int tid = threadIdx.x;
    const float* hpb = HP + ((size_t)b * 256 + tt * 16) * 256;
    const float* epb = EP + ((size_t)b * 256 + it * 16) * 256;
#pragma unroll
    for (int l = 0; l < 4; ++l) {
        int idx = tid + l * 256;
        int r = idx >> 6, c4 = idx & 63;
        float4 hv = *(const float4*)(hpb + r * 256 + c4 * 4);
        *(float4*)&hp_s[r][c4 * 4] = hv;
        float4 ev = *(const float4*)(epb + r * 256 + c4 * 4);
        *(float4*)&ep_s[r][c4 * 4] = ev;
    }
    v_s[tid] = v[tid];
    __syncthreads();
    int tl = tid >> 4, il = tid & 15;
    float acc = 0.f;
#pragma unroll 4
    for (int d = 0; d < 256; ++d)
        acc += v_s[d] * ftanh_(hp_s[tl][d] + ep_s[il][d]);
    out[((size_t)b * 256 + tt * 16 + tl) * 256 + it * 16 + il] = acc;
}

// ---------------------------------------------------------------------------
extern "C" void kernel_launch(void* const* d_in, const int* in_sizes, int n_in,
                              void* d_out, int out_size, void* d_ws, size_t ws_size,
                              hipStream_t stream)
{
    const float* parts    = (const float*)d_in[0];
    const float* bin_info = (const float*)d_in[1];
    const int*   target   = (const int*)d_in[2];
    const float* pe_W1 = (const float*)d_in[3];
    const float* pe_b1 = (const float*)d_in[4];
    const float* pe_W2 = (const float*)d_in[5];
    const float* pe_b2 = (const float*)d_in[6];
    const float* be_W1 = (const float*)d_in[7];
    const float* be_b1 = (const float*)d_in[8];
    const float* be_W2 = (const float*)d_in[9];
    const float* be_b2 = (const float*)d_in[10];
    const float* pos_emb = (const float*)d_in[11];
    const float* tr_Wqkv = (const float*)d_in[12];
    const float* tr_bqkv = (const float*)d_in[13];
    const float* tr_Wo   = (const float*)d_in[14];
    const float* tr_bo   = (const float*)d_in[15];
    const float* tr_ln1_g = (const float*)d_in[16];
    const float* tr_ln1_b = (const float*)d_in[17];
    const float* tr_ff_W1 = (const float*)d_in[18];
    const float* tr_ff_b1 = (const float*)d_in[19];
    const float* tr_ff_W2 = (const float*)d_in[20];
    const float* tr_ff_b2 = (const float*)d_in[21];
    const float* tr_ln2_g = (const float*)d_in[22];
    const float* tr_ln2_b = (const float*)d_in[23];
    const float* lstm_Wih = (const float*)d_in[24];
    const float* lstm_Whh = (const float*)d_in[25];
    const float* lstm_bih = (const float*)d_in[26];
    const float* lstm_bhh = (const float*)d_in[27];
    const float* ptr_W = (const float*)d_in[28];
    const float* ptr_b = (const float*)d_in[29];
    const float* ptr_v = (const float*)d_in[30];

    float* ws = (float*)d_ws;
    float* X     = ws;                   // 2,097,152
    float* S1    = X + 2097152;          // 8,388,608
    float* S2    = S1 + 8388608;         // 2,097,152
    float* EPROJ = S2 + 2097152;         // 2,097,152
    float* BBuf  = EPROJ + 2097152;      // 2048
    float* WQf   = BBuf + 2048;          // 131,072 (uint)
    float* HALL  = WQf + 131072;         // 2,097,152
    float* H2f   = HALL + 2097152;       // 1,048,576 (uint)
    float* FLG   = H2f + 1048576;        // 8,192 (int)
    // total ~17.9M floats ≈ 71.5 MB

    // ---- encoders ----
    bin_enc_kernel<<<32, 64, 0, stream>>>(bin_info, be_W1, be_b1, be_W2, be_b2, BBuf);
    part_enc_kernel<<<256, 128, 0, stream>>>(parts, pe_W1, pe_b1, pe_W2, pe_b2,
                                             BBuf, pos_emb, X);

    // ---- transformer layers ----
    for (int l = 0; l < 3; ++l) {
        gemm_kernel<128, false><<<dim3(64, 6), 256, 0, stream>>>(
            X, tr_Wqkv + (size_t)l * 768 * 256, tr_bqkv + l * 768, nullptr,
            S1, 8192, 768, 256);
        attn_kernel<<<256, 256, 0, stream>>>(S1, S2);
        gemm_kernel<64, false><<<dim3(64, 4), 256, 0, stream>>>(
            S2, tr_Wo + (size_t)l * 256 * 256, tr_bo + l * 256, nullptr,
            S1, 8192, 256, 256);
        add_ln_kernel<<<8192, 256, 0, stream>>>(X, S1, tr_ln1_g + l * 256,
                                                tr_ln1_b + l * 256);
        gemm_kernel<128, true><<<dim3(64, 4), 256, 0, stream>>>(
            X, tr_ff_W1 + (size_t)l * 512 * 256, tr_ff_b1 + l * 512, nullptr,
            S1, 8192, 512, 256);
        gemm_kernel<64, false><<<dim3(64, 4), 256, 0, stream>>>(
            S1, tr_ff_W2 + (size_t)l * 256 * 512, tr_ff_b2 + l * 256, nullptr,
            S2, 8192, 256, 512);
        add_ln_kernel<<<8192, 256, 0, stream>>>(X, S2, tr_ln2_g + l * 256,
                                                tr_ln2_b + l * 256);
    }

    // ---- pointer decode ----
    gemm_kernel<64, false><<<dim3(64, 4), 256, 0, stream>>>(
        X, ptr_W, ptr_b, nullptr, EPROJ, 8192, 256, 256);
    gather_kernel<<<8192, 256, 0, stream>>>(X, target, S2);
    gemm_kernel<128, false><<<dim3(64, 8), 256, 0, stream>>>(
        S2, lstm_Wih, lstm_bih, lstm_bhh, S1, 8192, 1024, 256);
    wcvt_f16_kernel<<<512, 256, 0, stream>>>(lstm_Whh, (unsigned int*)WQf);
    clear_flags_kernel<<<32, 256, 0, stream>>>((int*)FLG);
    lstm_kernel<<<128, 256, 0, stream>>>(S1, (const unsigned int*)WQf, HALL,
                                         (unsigned int*)H2f, (int*)FLG);
    gemm_kernel<64, false><<<dim3(64, 4), 256, 0, stream>>>(
        HALL, ptr_W, ptr_b, nullptr, S2, 8192, 256, 256);
    pointer_kernel<<<dim3(16, 16, 32), 256, 0, stream>>>(S2, EPROJ, ptr_v,
                                                         (float*)d_out);
}

// Round 4
// 1705.535 us; speedup vs baseline: 2.6209x; 2.6209x over previous
//
#include <hip/hip_runtime.h>
#include <cstddef>

#define DEV __device__ __forceinline__

DEV float fexp2(float x) { return __builtin_amdgcn_exp2f(x); }
DEV float frcp(float x)  { return __builtin_amdgcn_rcpf(x); }
DEV float fsigm(float x) { return frcp(1.0f + fexp2(-1.44269504f * x)); }
DEV float ftanh_(float x){ return 1.0f - 2.0f * frcp(1.0f + fexp2(2.88539008f * x)); }

typedef _Float16 h2t __attribute__((ext_vector_type(2)));
union U32H2 { unsigned int u; h2t h; };
DEV h2t u2h(unsigned int u) { U32H2 x; x.u = u; return x.h; }

// ---------------------------------------------------------------------------
// Generic fp32 GEMM: C[M,N] = A[M,K] @ W[N,K]^T + bias1 (+bias2), optional relu
// ---------------------------------------------------------------------------
template <int BN, bool RELU>
__global__ __launch_bounds__(256) void gemm_kernel(
    const float* __restrict__ A, const float* __restrict__ W,
    const float* __restrict__ bias1, const float* __restrict__ bias2,
    float* __restrict__ C, int M, int N, int K)
{
    constexpr int BM = 128, BK = 16;
    constexpr int NC = BN / 64;
    __shared__ float As[BK][BM + 4];
    __shared__ float Bs[BK][BN + 4];

    const int tid = threadIdx.x;
    const int tx = tid & 15, ty = tid >> 4;
    const int m0 = blockIdx.x * BM, n0 = blockIdx.y * BN;

    float acc[2][NC][4][4];
#pragma unroll
    for (int rh = 0; rh < 2; ++rh)
#pragma unroll
        for (int ch = 0; ch < NC; ++ch)
#pragma unroll
            for (int i = 0; i < 4; ++i)
#pragma unroll
                for (int j = 0; j < 4; ++j) acc[rh][ch][i][j] = 0.f;

    for (int k0 = 0; k0 < K; k0 += BK) {
#pragma unroll
        for (int l = 0; l < 2; ++l) {
            int idx = tid + l * 256;
            int row = idx >> 2, kc4 = idx & 3;
            float4 v = *(const float4*)&A[(size_t)(m0 + row) * K + k0 + kc4 * 4];
            As[kc4 * 4 + 0][row] = v.x; As[kc4 * 4 + 1][row] = v.y;
            As[kc4 * 4 + 2][row] = v.z; As[kc4 * 4 + 3][row] = v.w;
        }
#pragma unroll
        for (int l = 0; l < BN / 64; ++l) {
            int idx = tid + l * 256;
            int row = idx >> 2, kc4 = idx & 3;
            float4 v = *(const float4*)&W[(size_t)(n0 + row) * K + k0 + kc4 * 4];
            Bs[kc4 * 4 + 0][row] = v.x; Bs[kc4 * 4 + 1][row] = v.y;
            Bs[kc4 * 4 + 2][row] = v.z; Bs[kc4 * 4 + 3][row] = v.w;
        }
        __syncthreads();
#pragma unroll
        for (int kk = 0; kk < BK; ++kk) {
            const float4 a0 = *(const float4*)&As[kk][ty * 4];
            const float4 a1 = *(const float4*)&As[kk][64 + ty * 4];
            float ar[2][4] = {{a0.x, a0.y, a0.z, a0.w}, {a1.x, a1.y, a1.z, a1.w}};
            float br[NC][4];
            const float4 b0 = *(const float4*)&Bs[kk][tx * 4];
            br[0][0] = b0.x; br[0][1] = b0.y; br[0][2] = b0.z; br[0][3] = b0.w;
            if (NC == 2) {
                const float4 b1 = *(const float4*)&Bs[kk][64 + tx * 4];
                br[1][0] = b1.x; br[1][1] = b1.y; br[1][2] = b1.z; br[1][3] = b1.w;
            }
#pragma unroll
            for (int rh = 0; rh < 2; ++rh)
#pragma unroll
                for (int ch = 0; ch < NC; ++ch)
#pragma unroll
                    for (int i = 0; i < 4; ++i)
#pragma unroll
                        for (int j = 0; j < 4; ++j)
                            acc[rh][ch][i][j] += ar[rh][i] * br[ch][j];
        }
        __syncthreads();
    }

#pragma unroll
    for (int ch = 0; ch < NC; ++ch) {
        int col = n0 + ch * 64 + tx * 4;
        float4 bv = *(const float4*)&bias1[col];
        if (bias2) {
            float4 b2 = *(const float4*)&bias2[col];
            bv.x += b2.x; bv.y += b2.y; bv.z += b2.z; bv.w += b2.w;
        }
#pragma unroll
        for (int rh = 0; rh < 2; ++rh)
#pragma unroll
            for (int i = 0; i < 4; ++i) {
                int row = m0 + rh * 64 + ty * 4 + i;
                float4 r;
                r.x = acc[rh][ch][i][0] + bv.x;
                r.y = acc[rh][ch][i][1] + bv.y;
                r.z = acc[rh][ch][i][2] + bv.z;
                r.w = acc[rh][ch][i][3] + bv.w;
                if (RELU) {
                    r.x = fmaxf(r.x, 0.f); r.y = fmaxf(r.y, 0.f);
                    r.z = fmaxf(r.z, 0.f); r.w = fmaxf(r.w, 0.f);
                }
                *(float4*)&C[(size_t)row * N + col] = r;
            }
    }
}

// ---------------------------------------------------------------------------
__global__ __launch_bounds__(64) void bin_enc_kernel(
    const float* __restrict__ bin_info, const float* __restrict__ W1,
    const float* __restrict__ b1, const float* __restrict__ W2,
    const float* __restrict__ b2, float* __restrict__ BBo)
{
    int b = blockIdx.x, d = threadIdx.x;
    __shared__ float h1[64];
    float x0 = bin_info[b * 2], x1 = bin_info[b * 2 + 1];
    h1[d] = fmaxf(W1[d * 2] * x0 + W1[d * 2 + 1] * x1 + b1[d], 0.f);
    __syncthreads();
    float acc = b2[d];
#pragma unroll 4
    for (int e = 0; e < 64; ++e) acc += W2[d * 64 + e] * h1[e];
    BBo[b * 64 + d] = acc;
}

// ---------------------------------------------------------------------------
__global__ __launch_bounds__(128) void part_enc_kernel(
    const float* __restrict__ parts, const float* __restrict__ W1,
    const float* __restrict__ b1, const float* __restrict__ W2,
    const float* __restrict__ b2, const float* __restrict__ BBi,
    const float* __restrict__ pos_emb, float* __restrict__ X)
{
    __shared__ float W2s[128][129];
    __shared__ float h1[128];
    __shared__ float pin[16];
    int tid = threadIdx.x;
    int b = blockIdx.x >> 3, s0 = (blockIdx.x & 7) * 32;
    for (int l = 0; l < 128; ++l) W2s[l][tid] = W2[l * 128 + tid];
    float w1r[16];
#pragma unroll
    for (int k = 0; k < 16; ++k) w1r[k] = W1[tid * 16 + k];
    float bias1v = b1[tid], bias2v = b2[tid];
    for (int si = 0; si < 32; ++si) {
        int s = s0 + si;
        size_t row = (size_t)b * 256 + s;
        if (tid < 16) pin[tid] = parts[row * 16 + tid];
        __syncthreads();
        float h = bias1v;
#pragma unroll
        for (int k = 0; k < 16; ++k) h += w1r[k] * pin[k];
        h1[tid] = fmaxf(h, 0.f);
        __syncthreads();
        float acc = bias2v;
#pragma unroll 4
        for (int e = 0; e < 128; ++e) acc += W2s[tid][e] * h1[e];
        X[row * 256 + tid] = acc;
        if (tid < 64) {
            X[row * 256 + 128 + tid] = BBi[b * 64 + tid];
            X[row * 256 + 192 + tid] = pos_emb[s * 64 + tid];
        }
        __syncthreads();
    }
}

// ---------------------------------------------------------------------------
__global__ __launch_bounds__(256) void attn_kernel(
    const float* __restrict__ QKV, float* __restrict__ O)
{
    int bh = blockIdx.x;
    int b = bh >> 3, h = bh & 7;
    int s = threadIdx.x;
    __shared__ float k_s[256][36];
    __shared__ float v_s[256][36];
    const float scale = 0.17677669529663687f;
    const float c_log2e = 1.44269504f;

    const float* base = QKV + ((size_t)(b * 256 + s)) * 768 + h * 32;
    float q[32];
#pragma unroll
    for (int d4 = 0; d4 < 8; ++d4) {
        float4 qv = *(const float4*)(base + d4 * 4);
        q[d4 * 4 + 0] = qv.x; q[d4 * 4 + 1] = qv.y;
        q[d4 * 4 + 2] = qv.z; q[d4 * 4 + 3] = qv.w;
        float4 kv = *(const float4*)(base + 256 + d4 * 4);
        *(float4*)&k_s[s][d4 * 4] = kv;
        float4 vv = *(const float4*)(base + 512 + d4 * 4);
        *(float4*)&v_s[s][d4 * 4] = vv;
    }
    __syncthreads();

    float mmax = -1e30f;
    for (int j = 0; j < 256; ++j) {
        float sc = 0.f;
#pragma unroll
        for (int d4 = 0; d4 < 8; ++d4) {
            float4 kv = *(const float4*)&k_s[j][d4 * 4];
            sc += q[d4 * 4 + 0] * kv.x + q[d4 * 4 + 1] * kv.y
                + q[d4 * 4 + 2] * kv.z + q[d4 * 4 + 3] * kv.w;
        }
        mmax = fmaxf(mmax, sc);
    }
    float sum = 0.f;
    float o[32];
#pragma unroll
    for (int d = 0; d < 32; ++d) o[d] = 0.f;
    for (int j = 0; j < 256; ++j) {
        float sc = 0.f;
#pragma unroll
        for (int d4 = 0; d4 < 8; ++d4) {
            float4 kv = *(const float4*)&k_s[j][d4 * 4];
            sc += q[d4 * 4 + 0] * kv.x + q[d4 * 4 + 1] * kv.y
                + q[d4 * 4 + 2] * kv.z + q[d4 * 4 + 3] * kv.w;
        }
        float e = fexp2((sc - mmax) * (scale * c_log2e));
        sum += e;
#pragma unroll
        for (int d4 = 0; d4 < 8; ++d4) {
            float4 vv = *(const float4*)&v_s[j][d4 * 4];
            o[d4 * 4 + 0] += e * vv.x; o[d4 * 4 + 1] += e * vv.y;
            o[d4 * 4 + 2] += e * vv.z; o[d4 * 4 + 3] += e * vv.w;
        }
    }
    float inv = 1.0f / sum;
    float* op = O + ((size_t)(b * 256 + s)) * 256 + h * 32;
#pragma unroll
    for (int d4 = 0; d4 < 8; ++d4) {
        float4 r;
        r.x = o[d4 * 4 + 0] * inv; r.y = o[d4 * 4 + 1] * inv;
        r.z = o[d4 * 4 + 2] * inv; r.w = o[d4 * 4 + 3] * inv;
        *(float4*)(op + d4 * 4) = r;
    }
}

// ---------------------------------------------------------------------------
__global__ __launch_bounds__(256) void add_ln_kernel(
    float* __restrict__ X, const float* __restrict__ R,
    const float* __restrict__ g, const float* __restrict__ beta)
{
    size_t row = blockIdx.x;
    int d = threadIdx.x;
    float y = X[row * 256 + d] + R[row * 256 + d];
    float s = y, s2 = y * y;
#pragma unroll
    for (int o = 32; o; o >>= 1) {
        s += __shfl_down(s, o);
        s2 += __shfl_down(s2, o);
    }
    __shared__ float red[8];
    int wid = d >> 6, lane = d & 63;
    if (lane == 0) { red[wid] = s; red[4 + wid] = s2; }
    __syncthreads();
    if (d == 0) {
        float a = 0.f, b2 = 0.f;
        for (int w = 0; w < 4; ++w) { a += red[w]; b2 += red[4 + w]; }
        red[0] = a * (1.f / 256.f);
        red[1] = b2 * (1.f / 256.f);
    }
    __syncthreads();
    float m = red[0];
    float var = red[1] - m * m;
    float inv = rsqrtf(var + 1e-5f);
    X[row * 256 + d] = (y - m) * inv * g[d] + beta[d];
}

// ---------------------------------------------------------------------------
__global__ __launch_bounds__(256) void gather_kernel(
    const float* __restrict__ X, const int* __restrict__ target,
    float* __restrict__ Xg)
{
    int row = blockIdx.x;
    int b = row >> 8, t = row & 255;
    int d = threadIdx.x;
    float val = 0.f;
    if (t > 0) {
        int src = target[b * 256 + t - 1];
        val = X[((size_t)b * 256 + src) * 256 + d];
    }
    Xg[(size_t)row * 256 + d] = val;
}

// ---------------------------------------------------------------------------
// Whh fp32 [1024,256] -> f16x2 blob WB (uint[131072] = 64 uint4-slots x 512
// threads). Thread (tid in [0,512)) owns rows r = 4*(tid&255)+i (i<4) and
// k-range [128*kh, 128*kh+128) with kh = tid>>8.
// Word (i,c,l): k = 128*kh + 8*c + 2*l, c in [0,16), l in [0,4).
// uint4-slot q: q<8: LDS part, q = i*2+c (c<2)
//              q in [8,44): reg part, q-8 = i*9+(c-2) (c in [2,11))
//              q in [44,64): stream part, q-44 = (c-11)*4+i (c in [11,16))
// Flat uint index = (q*512 + tid)*4 + l.
// ---------------------------------------------------------------------------
__global__ __launch_bounds__(256) void wcvt2_kernel(
    const float* __restrict__ Whh, unsigned int* __restrict__ WB)
{
    int idx = blockIdx.x * 256 + threadIdx.x;  // 0..131071
    int l = idx & 3;
    int gt = idx >> 2;
    int tid = gt & 511;
    int q = gt >> 9;                            // 0..63
    int i, c;
    if (q < 8)       { i = q >> 1; c = q & 1; }
    else if (q < 44) { int qq = q - 8; i = qq / 9; c = 2 + qq % 9; }
    else             { int qq = q - 44; c = 11 + (qq >> 2); i = qq & 3; }
    int r = ((tid & 255) << 2) + i;
    int k = ((tid >> 8) << 7) + (c << 3) + (l << 1);
    _Float16 lo = (_Float16)Whh[r * 256 + k];
    _Float16 hi = (_Float16)Whh[r * 256 + k + 1];
    U32H2 x; x.h = h2t{lo, hi};
    WB[idx] = x.u;
}

// ---------------------------------------------------------------------------
// LSTM recurrence: 1 block/batch, 512 threads (8 waves), all weight state
// local to the CU: 64 KB in LDS + 144 VGPRs/thread + 160 KB/step streamed
// from L2 (shared across all 32 blocks). h kept f16x2-packed in LDS.
// ---------------------------------------------------------------------------
__global__ __launch_bounds__(512) void lstm_kernel(
    const float* __restrict__ g_in, const uint4* __restrict__ WB4,
    float* __restrict__ HALL)
{
    const int b = blockIdx.x;
    const int tid = threadIdx.x;
    const int kh = tid >> 8, j4 = tid & 255;

    __shared__ uint4 WL4[4096];        // 64 KB
    __shared__ float gpart[2][1024];   // 8 KB
    __shared__ uint4 h2v[32];          // 512 B (128 f16x2 words)
    unsigned int* h2_s = (unsigned int*)h2v;

    // one-time LDS weight load (q in [0,8))
#pragma unroll
    for (int g = 0; g < 8; ++g) WL4[g * 512 + tid] = WB4[g * 512 + tid];
    // one-time register weight load (q in [8,44))
    uint4 wr[36];
#pragma unroll
    for (int q = 0; q < 36; ++q) wr[q] = WB4[(8 + q) * 512 + tid];
    if (tid < 128) h2_s[tid] = 0u;

    const float* ginb = g_in + (size_t)b * 256 * 1024;
    float gi0 = 0.f, gi1 = 0.f, gi2 = 0.f, gi3 = 0.f;
    if (tid < 256) {
        gi0 = ginb[tid];       gi1 = ginb[tid + 256];
        gi2 = ginb[tid + 512]; gi3 = ginb[tid + 768];
    }
    float c_state = 0.f;
    const uint4* SW4 = WB4 + 44 * 512;
    __syncthreads();

    for (int t = 0; t < 256; ++t) {
        // issue streamed weight loads (c-major: sw[(c-11)*4+i])
        uint4 sw[20];
#pragma unroll
        for (int q = 0; q < 8; ++q) sw[q] = SW4[q * 512 + tid];

        float acc[4] = {0.f, 0.f, 0.f, 0.f};
#pragma unroll
        for (int c = 0; c < 16; ++c) {
            if (c == 4) {
#pragma unroll
                for (int q = 8; q < 20; ++q) sw[q] = SW4[q * 512 + tid];
            }
            uint4 h4 = h2v[(kh << 4) + c];
            h2t hx = u2h(h4.x), hy = u2h(h4.y), hz = u2h(h4.z), hw = u2h(h4.w);
#pragma unroll
            for (int i = 0; i < 4; ++i) {
                uint4 w = (c < 2)  ? WL4[((i << 1) + c) * 512 + tid]
                        : (c < 11) ? wr[i * 9 + (c - 2)]
                                   : sw[((c - 11) << 2) + i];
                acc[i] = __builtin_amdgcn_fdot2(u2h(w.x), hx, acc[i], false);
                acc[i] = __builtin_amdgcn_fdot2(u2h(w.y), hy, acc[i], false);
                acc[i] = __builtin_amdgcn_fdot2(u2h(w.z), hz, acc[i], false);
                acc[i] = __builtin_amdgcn_fdot2(u2h(w.w), hw, acc[i], false);
            }
        }
        *(float4*)&gpart[kh][j4 << 2] = make_float4(acc[0], acc[1], acc[2], acc[3]);
        __syncthreads();

        if (tid < 256) {
            int j = tid;
            float ig = gi0 + gpart[0][j]       + gpart[1][j];
            float fg = gi1 + gpart[0][j + 256] + gpart[1][j + 256];
            float gg = gi2 + gpart[0][j + 512] + gpart[1][j + 512];
            float og = gi3 + gpart[0][j + 768] + gpart[1][j + 768];
            c_state = fsigm(fg) * c_state + fsigm(ig) * ftanh_(gg);
            float h = fsigm(og) * ftanh_(c_state);
            HALL[((size_t)(b * 256 + t)) * 256 + j] = h;
            U32H2 hxp; hxp.h = h2t{(_Float16)h, (_Float16)0.f};
            unsigned int hu = hxp.u & 0xffffu;
            unsigned int other = (unsigned int)__shfl_xor((int)hu, 1);
            if ((j & 1) == 0) h2_s[j >> 1] = hu | (other << 16);
            // prefetch next step's gate inputs
            int tn = (t < 255) ? (t + 1) : 255;
            const float* gnext = ginb + (size_t)tn * 1024;
            gi0 = gnext[j];       gi1 = gnext[j + 256];
            gi2 = gnext[j + 512]; gi3 = gnext[j + 768];
        }
        __syncthreads();
    }
}

// ---------------------------------------------------------------------------
__global__ __launch_bounds__(256) void pointer_kernel(
    const float* __restrict__ HP, const float* __restrict__ EP,
    const float* __restrict__ v, float* __restrict__ out)
{
    int b = blockIdx.z, tt = blockIdx.y, it = blockIdx.x;
    __shared__ float hp_s[16][260];
    __shared__ float ep_s[16][260];
    __shared__ float v_s[256];
    int tid = threadIdx.x;
    const float* hpb = HP + ((size_t)b * 256 + tt * 16) * 256;
    const float* epb = EP + ((size_t)b * 256 + it * 16) * 256;
#pragma unroll
    for (int l = 0; l < 4; ++l) {
        int idx = tid + l * 256;
        int r = idx >> 6, c4 = idx & 63;
        float4 hv = *(const float4*)(hpb + r * 256 + c4 * 4);
        *(float4*)&hp_s[r][c4 * 4] = hv;
        float4 ev = *(const float4*)(epb + r * 256 + c4 * 4);
        *(float4*)&ep_s[r][c4 * 4] = ev;
    }
    v_s[tid] = v[tid];
    __syncthreads();
    int tl = tid >> 4, il = tid & 15;
    float acc = 0.f;
#pragma unroll 4
    for (int d = 0; d < 256; ++d)
        acc += v_s[d] * ftanh_(hp_s[tl][d] + ep_s[il][d]);
    out[((size_t)b * 256 + tt * 16 + tl) * 256 + it * 16 + il] = acc;
}

// ---------------------------------------------------------------------------
extern "C" void kernel_launch(void* const* d_in, const int* in_sizes, int n_in,
                              void* d_out, int out_size, void* d_ws, size_t ws_size,
                              hipStream_t stream)
{
    const float* parts    = (const float*)d_in[0];
    const float* bin_info = (const float*)d_in[1];
    const int*   target   = (const int*)d_in[2];
    const float* pe_W1 = (const float*)d_in[3];
    const float* pe_b1 = (const float*)d_in[4];
    const float* pe_W2 = (const float*)d_in[5];
    const float* pe_b2 = (const float*)d_in[6];
    const float* be_W1 = (const float*)d_in[7];
    const float* be_b1 = (const float*)d_in[8];
    const float* be_W2 = (const float*)d_in[9];
    const float* be_b2 = (const float*)d_in[10];
    const float* pos_emb = (const float*)d_in[11];
    const float* tr_Wqkv = (const float*)d_in[12];
    const float* tr_bqkv = (const float*)d_in[13];
    const float* tr_Wo   = (const float*)d_in[14];
    const float* tr_bo   = (const float*)d_in[15];
    const float* tr_ln1_g = (const float*)d_in[16];
    const float* tr_ln1_b = (const float*)d_in[17];
    const float* tr_ff_W1 = (const float*)d_in[18];
    const float* tr_ff_b1 = (const float*)d_in[19];
    const float* tr_ff_W2 = (const float*)d_in[20];
    const float* tr_ff_b2 = (const float*)d_in[21];
    const float* tr_ln2_g = (const float*)d_in[22];
    const float* tr_ln2_b = (const float*)d_in[23];
    const float* lstm_Wih = (const float*)d_in[24];
    const float* lstm_Whh = (const float*)d_in[25];
    const float* lstm_bih = (const float*)d_in[26];
    const float* lstm_bhh = (const float*)d_in[27];
    const float* ptr_W = (const float*)d_in[28];
    const float* ptr_b = (const float*)d_in[29];
    const float* ptr_v = (const float*)d_in[30];

    float* ws = (float*)d_ws;
    float* X     = ws;                   // 2,097,152
    float* S1    = X + 2097152;          // 8,388,608
    float* S2    = S1 + 8388608;         // 2,097,152
    float* EPROJ = S2 + 2097152;         // 2,097,152
    float* BBuf  = EPROJ + 2097152;      // 2048
    float* WBf   = BBuf + 2048;          // 131,072 uints (512 KB)
    float* HALL  = WBf + 131072;         // 2,097,152

    // ---- encoders ----
    bin_enc_kernel<<<32, 64, 0, stream>>>(bin_info, be_W1, be_b1, be_W2, be_b2, BBuf);
    part_enc_kernel<<<256, 128, 0, stream>>>(parts, pe_W1, pe_b1, pe_W2, pe_b2,
                                             BBuf, pos_emb, X);

    // ---- transformer layers ----
    for (int l = 0; l < 3; ++l) {
        gemm_kernel<128, false><<<dim3(64, 6), 256, 0, stream>>>(
            X, tr_Wqkv + (size_t)l * 768 * 256, tr_bqkv + l * 768, nullptr,
            S1, 8192, 768, 256);
        attn_kernel<<<256, 256, 0, stream>>>(S1, S2);
        gemm_kernel<64, false><<<dim3(64, 4), 256, 0, stream>>>(
            S2, tr_Wo + (size_t)l * 256 * 256, tr_bo + l * 256, nullptr,
            S1, 8192, 256, 256);
        add_ln_kernel<<<8192, 256, 0, stream>>>(X, S1, tr_ln1_g + l * 256,
                                                tr_ln1_b + l * 256);
        gemm_kernel<128, true><<<dim3(64, 4), 256, 0, stream>>>(
            X, tr_ff_W1 + (size_t)l * 512 * 256, tr_ff_b1 + l * 512, nullptr,
            S1, 8192, 512, 256);
        gemm_kernel<64, false><<<dim3(64, 4), 256, 0, stream>>>(
            S1, tr_ff_W2 + (size_t)l * 256 * 512, tr_ff_b2 + l * 256, nullptr,
            S2, 8192, 256, 512);
        add_ln_kernel<<<8192, 256, 0, stream>>>(X, S2, tr_ln2_g + l * 256,
                                                tr_ln2_b + l * 256);
    }

    // ---- pointer decode ----
    gemm_kernel<64, false><<<dim3(64, 4), 256, 0, stream>>>(
        X, ptr_W, ptr_b, nullptr, EPROJ, 8192, 256, 256);
    gather_kernel<<<8192, 256, 0, stream>>>(X, target, S2);
    gemm_kernel<128, false><<<dim3(64, 8), 256, 0, stream>>>(
        S2, lstm_Wih, lstm_bih, lstm_bhh, S1, 8192, 1024, 256);
    wcvt2_kernel<<<512, 256, 0, stream>>>(lstm_Whh, (unsigned int*)WBf);
    lstm_kernel<<<32, 512, 0, stream>>>(S1, (const uint4*)WBf, HALL);
    gemm_kernel<64, false><<<dim3(64, 4), 256, 0, stream>>>(
        HALL, ptr_W, ptr_b, nullptr, S2, 8192, 256, 256);
    pointer_kernel<<<dim3(16, 16, 32), 256, 0, stream>>>(S2, EPROJ, ptr_v,
                                                         (float*)d_out);
}

// Round 5
// 1486.732 us; speedup vs baseline: 3.0066x; 1.1472x over previous
//
#include <hip/hip_runtime.h>
#include <cstddef>

#define DEV __device__ __forceinline__

DEV float fexp2(float x) { return __builtin_amdgcn_exp2f(x); }
DEV float frcp(float x)  { return __builtin_amdgcn_rcpf(x); }
DEV float fsigm(float x) { return frcp(1.0f + fexp2(-1.44269504f * x)); }
DEV float ftanh_(float x){ return 1.0f - 2.0f * frcp(1.0f + fexp2(2.88539008f * x)); }

typedef _Float16 h2t __attribute__((ext_vector_type(2)));
typedef _Float16 v8h __attribute__((ext_vector_type(8)));
typedef float v4f __attribute__((ext_vector_type(4)));
union U32H2 { unsigned int u; h2t h; };
DEV h2t u2h(unsigned int u) { U32H2 x; x.u = u; return x.h; }

// ---------------------------------------------------------------------------
// f16 MFMA GEMM: C[M,N] = A[M,K] @ W[N,K]^T + bias1 (+bias2); A,W f16 row-major
// (both K-contiguous), C fp32 or f16. BM=128, BK=32, 256 threads (4 waves in
// 2x2), wave tile 64 x BN/2 via 4 x (BN/32) mfma_f32_16x16x32_f16.
// Reg-staged LDS, next-iter global prefetch overlapped with MFMA.
// ---------------------------------------------------------------------------
template <int BN, bool RELU, bool OUTF16>
__global__ __launch_bounds__(256) void hgemm_kernel(
    const _Float16* __restrict__ A, const _Float16* __restrict__ W,
    const float* __restrict__ bias1, const float* __restrict__ bias2,
    void* __restrict__ Cout, int M, int N, int K)
{
    constexpr int NT = BN / 32;      // col tiles per wave
    constexpr int RB = BN / 64;      // B staging rounds
    __shared__ _Float16 As[128 * 32];
    __shared__ _Float16 Bs[BN * 32];

    const int tid = threadIdx.x;
    const int lane = tid & 63;
    const int lm = lane & 15, lq = lane >> 4;
    const int wrow = ((tid >> 6) & 1) * 64;
    const int wcol = (tid >> 7) * (BN / 2);
    const int m0 = blockIdx.x * 128, n0 = blockIdx.y * BN;
    const _Float16* Ab = A + (size_t)m0 * K;
    const _Float16* Wb = W + (size_t)n0 * K;

    v4f acc[4][NT];
#pragma unroll
    for (int i = 0; i < 4; ++i)
#pragma unroll
        for (int j = 0; j < NT; ++j) acc[i][j] = (v4f){0.f, 0.f, 0.f, 0.f};

    const int rowA0 = tid >> 2, qA0 = tid & 3;
    const int cc1 = 256 + tid, rowA1 = cc1 >> 2, qA1 = cc1 & 3;

    uint4 ra[2], rb[2];
    ra[0] = *(const uint4*)(Ab + (size_t)rowA0 * K + qA0 * 8);
    ra[1] = *(const uint4*)(Ab + (size_t)rowA1 * K + qA1 * 8);
    rb[0] = *(const uint4*)(Wb + (size_t)rowA0 * K + qA0 * 8);
    if (RB == 2) rb[1] = *(const uint4*)(Wb + (size_t)rowA1 * K + qA1 * 8);

    for (int k0 = 0; k0 < K; k0 += 32) {
        __syncthreads();
        *(uint4*)(As + (size_t)tid * 8) = ra[0];
        *(uint4*)(As + (size_t)(256 + tid) * 8) = ra[1];
        *(uint4*)(Bs + (size_t)tid * 8) = rb[0];
        if (RB == 2) *(uint4*)(Bs + (size_t)(256 + tid) * 8) = rb[1];
        __syncthreads();
        int kn = k0 + 32;
        if (kn < K) {
            ra[0] = *(const uint4*)(Ab + (size_t)rowA0 * K + kn + qA0 * 8);
            ra[1] = *(const uint4*)(Ab + (size_t)rowA1 * K + kn + qA1 * 8);
            rb[0] = *(const uint4*)(Wb + (size_t)rowA0 * K + kn + qA0 * 8);
            if (RB == 2) rb[1] = *(const uint4*)(Wb + (size_t)rowA1 * K + kn + qA1 * 8);
        }
        v8h af[4], bf[NT];
#pragma unroll
        for (int i = 0; i < 4; ++i)
            af[i] = *(const v8h*)(As + (size_t)(wrow + i * 16 + lm) * 32 + lq * 8);
#pragma unroll
        for (int j = 0; j < NT; ++j)
            bf[j] = *(const v8h*)(Bs + (size_t)(wcol + j * 16 + lm) * 32 + lq * 8);
#pragma unroll
        for (int i = 0; i < 4; ++i)
#pragma unroll
            for (int j = 0; j < NT; ++j)
                acc[i][j] = __builtin_amdgcn_mfma_f32_16x16x32_f16(
                    af[i], bf[j], acc[i][j], 0, 0, 0);
    }

#pragma unroll
    for (int j = 0; j < NT; ++j) {
        int col = n0 + wcol + j * 16 + lm;
        float bv = bias1[col];
        if (bias2) bv += bias2[col];
#pragma unroll
        for (int i = 0; i < 4; ++i) {
            int rbase = m0 + wrow + i * 16 + lq * 4;
#pragma unroll
            for (int rg = 0; rg < 4; ++rg) {
                float vv = acc[i][j][rg] + bv;
                if (RELU) vv = fmaxf(vv, 0.f);
                if (OUTF16)
                    ((_Float16*)Cout)[(size_t)(rbase + rg) * N + col] = (_Float16)vv;
                else
                    ((float*)Cout)[(size_t)(rbase + rg) * N + col] = vv;
            }
        }
    }
}

// ---------------------------------------------------------------------------
__global__ __launch_bounds__(256) void cvt_f16_kernel(
    const float* __restrict__ src, _Float16* __restrict__ dst, int n)
{
    int i = blockIdx.x * 256 + threadIdx.x;
    if (i < n) dst[i] = (_Float16)src[i];
}

// ---------------------------------------------------------------------------
__global__ __launch_bounds__(64) void bin_enc_kernel(
    const float* __restrict__ bin_info, const float* __restrict__ W1,
    const float* __restrict__ b1, const float* __restrict__ W2,
    const float* __restrict__ b2, float* __restrict__ BBo)
{
    int b = blockIdx.x, d = threadIdx.x;
    __shared__ float h1[64];
    float x0 = bin_info[b * 2], x1 = bin_info[b * 2 + 1];
    h1[d] = fmaxf(W1[d * 2] * x0 + W1[d * 2 + 1] * x1 + b1[d], 0.f);
    __syncthreads();
    float acc = b2[d];
#pragma unroll 4
    for (int e = 0; e < 64; ++e) acc += W2[d * 64 + e] * h1[e];
    BBo[b * 64 + d] = acc;
}

// ---------------------------------------------------------------------------
__global__ __launch_bounds__(128) void part_enc_kernel(
    const float* __restrict__ parts, const float* __restrict__ W1,
    const float* __restrict__ b1, const float* __restrict__ W2,
    const float* __restrict__ b2, const float* __restrict__ BBi,
    const float* __restrict__ pos_emb, float* __restrict__ X,
    _Float16* __restrict__ X16)
{
    __shared__ float W2s[128][129];
    __shared__ float h1[128];
    __shared__ float pin[16];
    int tid = threadIdx.x;
    int b = blockIdx.x >> 3, s0 = (blockIdx.x & 7) * 32;
    for (int l = 0; l < 128; ++l) W2s[l][tid] = W2[l * 128 + tid];
    float w1r[16];
#pragma unroll
    for (int k = 0; k < 16; ++k) w1r[k] = W1[tid * 16 + k];
    float bias1v = b1[tid], bias2v = b2[tid];
    for (int si = 0; si < 32; ++si) {
        int s = s0 + si;
        size_t row = (size_t)b * 256 + s;
        if (tid < 16) pin[tid] = parts[row * 16 + tid];
        __syncthreads();
        float h = bias1v;
#pragma unroll
        for (int k = 0; k < 16; ++k) h += w1r[k] * pin[k];
        h1[tid] = fmaxf(h, 0.f);
        __syncthreads();
        float acc = bias2v;
#pragma unroll 4
        for (int e = 0; e < 128; ++e) acc += W2s[tid][e] * h1[e];
        X[row * 256 + tid] = acc;
        X16[row * 256 + tid] = (_Float16)acc;
        if (tid < 64) {
            float bbv = BBi[b * 64 + tid];
            float pev = pos_emb[s * 64 + tid];
            X[row * 256 + 128 + tid] = bbv;
            X[row * 256 + 192 + tid] = pev;
            X16[row * 256 + 128 + tid] = (_Float16)bbv;
            X16[row * 256 + 192 + tid] = (_Float16)pev;
        }
        __syncthreads();
    }
}

// ---------------------------------------------------------------------------
// Attention (fp32 compute), output written as packed f16 pairs.
// ---------------------------------------------------------------------------
__global__ __launch_bounds__(256) void attn_kernel(
    const float* __restrict__ QKV, unsigned int* __restrict__ O16)
{
    int bh = blockIdx.x;
    int b = bh >> 3, h = bh & 7;
    int s = threadIdx.x;
    __shared__ float k_s[256][36];
    __shared__ float v_s[256][36];
    const float scale = 0.17677669529663687f;
    const float c_log2e = 1.44269504f;

    const float* base = QKV + ((size_t)(b * 256 + s)) * 768 + h * 32;
    float q[32];
#pragma unroll
    for (int d4 = 0; d4 < 8; ++d4) {
        float4 qv = *(const float4*)(base + d4 * 4);
        q[d4 * 4 + 0] = qv.x; q[d4 * 4 + 1] = qv.y;
        q[d4 * 4 + 2] = qv.z; q[d4 * 4 + 3] = qv.w;
        float4 kv = *(const float4*)(base + 256 + d4 * 4);
        *(float4*)&k_s[s][d4 * 4] = kv;
        float4 vv = *(const float4*)(base + 512 + d4 * 4);
        *(float4*)&v_s[s][d4 * 4] = vv;
    }
    __syncthreads();

    float mmax = -1e30f;
    for (int j = 0; j < 256; ++j) {
        float sc = 0.f;
#pragma unroll
        for (int d4 = 0; d4 < 8; ++d4) {
            float4 kv = *(const float4*)&k_s[j][d4 * 4];
            sc += q[d4 * 4 + 0] * kv.x + q[d4 * 4 + 1] * kv.y
                + q[d4 * 4 + 2] * kv.z + q[d4 * 4 + 3] * kv.w;
        }
        mmax = fmaxf(mmax, sc);
    }
    float sum = 0.f;
    float o[32];
#pragma unroll
    for (int d = 0; d < 32; ++d) o[d] = 0.f;
    for (int j = 0; j < 256; ++j) {
        float sc = 0.f;
#pragma unroll
        for (int d4 = 0; d4 < 8; ++d4) {
            float4 kv = *(const float4*)&k_s[j][d4 * 4];
            sc += q[d4 * 4 + 0] * kv.x + q[d4 * 4 + 1] * kv.y
                + q[d4 * 4 + 2] * kv.z + q[d4 * 4 + 3] * kv.w;
        }
        float e = fexp2((sc - mmax) * (scale * c_log2e));
        sum += e;
#pragma unroll
        for (int d4 = 0; d4 < 8; ++d4) {
            float4 vv = *(const float4*)&v_s[j][d4 * 4];
            o[d4 * 4 + 0] += e * vv.x; o[d4 * 4 + 1] += e * vv.y;
            o[d4 * 4 + 2] += e * vv.z; o[d4 * 4 + 3] += e * vv.w;
        }
    }
    float inv = 1.0f / sum;
    unsigned int* op = O16 + ((size_t)(b * 256 + s)) * 128 + h * 16;
#pragma unroll
    for (int p = 0; p < 16; ++p) {
        U32H2 x;
        x.h = h2t{(_Float16)(o[2 * p] * inv), (_Float16)(o[2 * p + 1] * inv)};
        op[p] = x.u;
    }
}

// ---------------------------------------------------------------------------
__global__ __launch_bounds__(256) void add_ln_kernel(
    float* __restrict__ X, const float* __restrict__ R,
    const float* __restrict__ g, const float* __restrict__ beta,
    _Float16* __restrict__ X16)
{
    size_t row = blockIdx.x;
    int d = threadIdx.x;
    float y = X[row * 256 + d] + R[row * 256 + d];
    float s = y, s2 = y * y;
#pragma unroll
    for (int o = 32; o; o >>= 1) {
        s += __shfl_down(s, o);
        s2 += __shfl_down(s2, o);
    }
    __shared__ float red[8];
    int wid = d >> 6, lane = d & 63;
    if (lane == 0) { red[wid] = s; red[4 + wid] = s2; }
    __syncthreads();
    if (d == 0) {
        float a = 0.f, b2 = 0.f;
        for (int w = 0; w < 4; ++w) { a += red[w]; b2 += red[4 + w]; }
        red[0] = a * (1.f / 256.f);
        red[1] = b2 * (1.f / 256.f);
    }
    __syncthreads();
    float m = red[0];
    float var = red[1] - m * m;
    float inv = rsqrtf(var + 1e-5f);
    float out = (y - m) * inv * g[d] + beta[d];
    X[row * 256 + d] = out;
    X16[row * 256 + d] = (_Float16)out;
}

// ---------------------------------------------------------------------------
__global__ __launch_bounds__(256) void gather_kernel(
    const float* __restrict__ X, const int* __restrict__ target,
    _Float16* __restrict__ Xg16)
{
    int row = blockIdx.x;
    int b = row >> 8, t = row & 255;
    int d = threadIdx.x;
    float val = 0.f;
    if (t > 0) {
        int src = target[b * 256 + t - 1];
        val = X[((size_t)b * 256 + src) * 256 + d];
    }
    Xg16[(size_t)row * 256 + d] = (_Float16)val;
}

// ---------------------------------------------------------------------------
// Whh fp32 [1024,256] -> f16x2 blob (see R4 layout comment)
// ---------------------------------------------------------------------------
__global__ __launch_bounds__(256) void wcvt2_kernel(
    const float* __restrict__ Whh, unsigned int* __restrict__ WB)
{
    int idx = blockIdx.x * 256 + threadIdx.x;  // 0..131071
    int l = idx & 3;
    int gt = idx >> 2;
    int tid = gt & 511;
    int q = gt >> 9;                            // 0..63
    int i, c;
    if (q < 8)       { i = q >> 1; c = q & 1; }
    else if (q < 44) { int qq = q - 8; i = qq / 9; c = 2 + qq % 9; }
    else             { int qq = q - 44; c = 11 + (qq >> 2); i = qq & 3; }
    int r = ((tid & 255) << 2) + i;
    int k = ((tid >> 8) << 7) + (c << 3) + (l << 1);
    _Float16 lo = (_Float16)Whh[r * 256 + k];
    _Float16 hi = (_Float16)Whh[r * 256 + k + 1];
    U32H2 x; x.h = h2t{lo, hi};
    WB[idx] = x.u;
}

// ---------------------------------------------------------------------------
// LSTM recurrence (R4 structure, f16 HALL output): 1 block/batch, 512 threads,
// weights CU-local: 64 KB LDS + 144 VGPR + 160 KB/step L2 stream.
// ---------------------------------------------------------------------------
__global__ __launch_bounds__(512) void lstm_kernel(
    const float* __restrict__ g_in, const uint4* __restrict__ WB4,
    _Float16* __restrict__ HALL16)
{
    const int b = blockIdx.x;
    const int tid = threadIdx.x;
    const int kh = tid >> 8, j4 = tid & 255;

    __shared__ uint4 WL4[4096];        // 64 KB
    __shared__ float gpart[2][1024];   // 8 KB
    __shared__ uint4 h2v[32];          // 512 B
    unsigned int* h2_s = (unsigned int*)h2v;

#pragma unroll
    for (int g = 0; g < 8; ++g) WL4[g * 512 + tid] = WB4[g * 512 + tid];
    uint4 wr[36];
#pragma unroll
    for (int q = 0; q < 36; ++q) wr[q] = WB4[(8 + q) * 512 + tid];
    if (tid < 128) h2_s[tid] = 0u;

    const float* ginb = g_in + (size_t)b * 256 * 1024;
    float gi0 = 0.f, gi1 = 0.f, gi2 = 0.f, gi3 = 0.f;
    if (tid < 256) {
        gi0 = ginb[tid];       gi1 = ginb[tid + 256];
        gi2 = ginb[tid + 512]; gi3 = ginb[tid + 768];
    }
    float c_state = 0.f;
    const uint4* SW4 = WB4 + 44 * 512;
    __syncthreads();

    for (int t = 0; t < 256; ++t) {
        uint4 sw[20];
#pragma unroll
        for (int q = 0; q < 8; ++q) sw[q] = SW4[q * 512 + tid];

        float acc[4] = {0.f, 0.f, 0.f, 0.f};
#pragma unroll
        for (int c = 0; c < 16; ++c) {
            if (c == 4) {
#pragma unroll
                for (int q = 8; q < 20; ++q) sw[q] = SW4[q * 512 + tid];
            }
            uint4 h4 = h2v[(kh << 4) + c];
            h2t hx = u2h(h4.x), hy = u2h(h4.y), hz = u2h(h4.z), hw = u2h(h4.w);
#pragma unroll
            for (int i = 0; i < 4; ++i) {
                uint4 w = (c < 2)  ? WL4[((i << 1) + c) * 512 + tid]
                        : (c < 11) ? wr[i * 9 + (c - 2)]
                                   : sw[((c - 11) << 2) + i];
                acc[i] = __builtin_amdgcn_fdot2(u2h(w.x), hx, acc[i], false);
                acc[i] = __builtin_amdgcn_fdot2(u2h(w.y), hy, acc[i], false);
                acc[i] = __builtin_amdgcn_fdot2(u2h(w.z), hz, acc[i], false);
                acc[i] = __builtin_amdgcn_fdot2(u2h(w.w), hw, acc[i], false);
            }
        }
        *(float4*)&gpart[kh][j4 << 2] = make_float4(acc[0], acc[1], acc[2], acc[3]);
        __syncthreads();

        if (tid < 256) {
            int j = tid;
            float ig = gi0 + gpart[0][j]       + gpart[1][j];
            float fg = gi1 + gpart[0][j + 256] + gpart[1][j + 256];
            float gg = gi2 + gpart[0][j + 512] + gpart[1][j + 512];
            float og = gi3 + gpart[0][j + 768] + gpart[1][j + 768];
            c_state = fsigm(fg) * c_state + fsigm(ig) * ftanh_(gg);
            float h = fsigm(og) * ftanh_(c_state);
            HALL16[((size_t)(b * 256 + t)) * 256 + j] = (_Float16)h;
            U32H2 hxp; hxp.h = h2t{(_Float16)h, (_Float16)0.f};
            unsigned int hu = hxp.u & 0xffffu;
            unsigned int other = (unsigned int)__shfl_xor((int)hu, 1);
            if ((j & 1) == 0) h2_s[j >> 1] = hu | (other << 16);
            int tn = (t < 255) ? (t + 1) : 255;
            const float* gnext = ginb + (size_t)tn * 1024;
            gi0 = gnext[j];       gi1 = gnext[j + 256];
            gi2 = gnext[j + 512]; gi3 = gnext[j + 768];
        }
        __syncthreads();
    }
}

// ---------------------------------------------------------------------------
__global__ __launch_bounds__(256) void pointer_kernel(
    const float* __restrict__ HP, const float* __restrict__ EP,
    const float* __restrict__ v, float* __restrict__ out)
{
    int b = blockIdx.z, tt = blockIdx.y, it = blockIdx.x;
    __shared__ float hp_s[16][260];
    __shared__ float ep_s[16][260];
    __shared__ float v_s[256];
    int tid = threadIdx.x;
    const float* hpb = HP + ((size_t)b * 256 + tt * 16) * 256;
    const float* epb = EP + ((size_t)b * 256 + it * 16) * 256;
#pragma unroll
    for (int l = 0; l < 4; ++l) {
        int idx = tid + l * 256;
        int r = idx >> 6, c4 = idx & 63;
        float4 hv = *(const float4*)(hpb + r * 256 + c4 * 4);
        *(float4*)&hp_s[r][c4 * 4] = hv;
        float4 ev = *(const float4*)(epb + r * 256 + c4 * 4);
        *(float4*)&ep_s[r][c4 * 4] = ev;
    }
    v_s[tid] = v[tid];
    __syncthreads();
    int tl = tid >> 4, il = tid & 15;
    float acc = 0.f;
#pragma unroll 4
    for (int d = 0; d < 256; ++d)
        acc += v_s[d] * ftanh_(hp_s[tl][d] + ep_s[il][d]);
    out[((size_t)b * 256 + tt * 16 + tl) * 256 + it * 16 + il] = acc;
}

// ---------------------------------------------------------------------------
extern "C" void kernel_launch(void* const* d_in, const int* in_sizes, int n_in,
                              void* d_out, int out_size, void* d_ws, size_t ws_size,
                              hipStream_t stream)
{
    const float* parts    = (const float*)d_in[0];
    const float* bin_info = (const float*)d_in[1];
    const int*   target   = (const int*)d_in[2];
    const float* pe_W1 = (const float*)d_in[3];
    const float* pe_b1 = (const float*)d_in[4];
    const float* pe_W2 = (const float*)d_in[5];
    const float* pe_b2 = (const float*)d_in[6];
    const float* be_W1 = (const float*)d_in[7];
    const float* be_b1 = (const float*)d_in[8];
    const float* be_W2 = (const float*)d_in[9];
    const float* be_b2 = (const float*)d_in[10];
    const float* pos_emb = (const float*)d_in[11];
    const float* tr_Wqkv = (const float*)d_in[12];
    const float* tr_bqkv = (const float*)d_in[13];
    const float* tr_Wo   = (const float*)d_in[14];
    const float* tr_bo   = (const float*)d_in[15];
    const float* tr_ln1_g = (const float*)d_in[16];
    const float* tr_ln1_b = (const float*)d_in[17];
    const float* tr_ff_W1 = (const float*)d_in[18];
    const float* tr_ff_b1 = (const float*)d_in[19];
    const float* tr_ff_W2 = (const float*)d_in[20];
    const float* tr_ff_b2 = (const float*)d_in[21];
    const float* tr_ln2_g = (const float*)d_in[22];
    const float* tr_ln2_b = (const float*)d_in[23];
    const float* lstm_Wih = (const float*)d_in[24];
    const float* lstm_Whh = (const float*)d_in[25];
    const float* lstm_bih = (const float*)d_in[26];
    const float* lstm_bhh = (const float*)d_in[27];
    const float* ptr_W = (const float*)d_in[28];
    const float* ptr_b = (const float*)d_in[29];
    const float* ptr_v = (const float*)d_in[30];

    // ---- workspace layout (floats); total ~17.96M floats ≈ 71.8 MB ----
    float* ws = (float*)d_ws;
    float* X     = ws;                        // 2,097,152
    float* S1    = X + 2097152;               // 8,388,608 (qkv f32 / g_in; S1_16 aliases)
    float* CF32  = S1 + 8388608;              // 2,097,152 (Wo/ff2 out, later HP)
    float* EPROJ = CF32 + 2097152;            // 2,097,152
    float* X16f  = EPROJ + 2097152;           // 1,048,576 (X16; later Xg16)
    float* S2f   = X16f + 1048576;            // 1,048,576 (attn out f16; later HALL16)
    float* W16f  = S2f + 1048576;             // 1,048,576 (f16 weight blob)
    float* WBf   = W16f + 1048576;            // 131,072 (lstm Whh blob)
    float* BBuf  = WBf + 131072;              // 2,048

    _Float16* X16    = (_Float16*)X16f;
    _Float16* Xg16   = X16;                   // alias, live after eproj GEMM
    _Float16* S2h    = (_Float16*)S2f;
    _Float16* HALL16 = S2h;                   // alias, live after layer loop
    _Float16* S1_16  = (_Float16*)S1;         // ff1 out aliases dead qkv
    _Float16* W16    = (_Float16*)W16f;
    _Float16* Wqkv16 = W16;                   // 589,824
    _Float16* Wo16   = Wqkv16 + 589824;       // 196,608
    _Float16* Wff116 = Wo16 + 196608;         // 393,216
    _Float16* Wff216 = Wff116 + 393216;       // 393,216
    _Float16* Wih16  = Wff216 + 393216;       // 262,144
    _Float16* WpW16  = Wih16 + 262144;        // 65,536

    // ---- one-time weight conversions ----
    cvt_f16_kernel<<<(589824 + 255) / 256, 256, 0, stream>>>(tr_Wqkv, Wqkv16, 589824);
    cvt_f16_kernel<<<(196608 + 255) / 256, 256, 0, stream>>>(tr_Wo, Wo16, 196608);
    cvt_f16_kernel<<<(393216 + 255) / 256, 256, 0, stream>>>(tr_ff_W1, Wff116, 393216);
    cvt_f16_kernel<<<(393216 + 255) / 256, 256, 0, stream>>>(tr_ff_W2, Wff216, 393216);
    cvt_f16_kernel<<<(262144 + 255) / 256, 256, 0, stream>>>(lstm_Wih, Wih16, 262144);
    cvt_f16_kernel<<<(65536 + 255) / 256, 256, 0, stream>>>(ptr_W, WpW16, 65536);
    wcvt2_kernel<<<512, 256, 0, stream>>>(lstm_Whh, (unsigned int*)WBf);

    // ---- encoders ----
    bin_enc_kernel<<<32, 64, 0, stream>>>(bin_info, be_W1, be_b1, be_W2, be_b2, BBuf);
    part_enc_kernel<<<256, 128, 0, stream>>>(parts, pe_W1, pe_b1, pe_W2, pe_b2,
                                             BBuf, pos_emb, X, X16);

    // ---- transformer layers ----
    for (int l = 0; l < 3; ++l) {
        hgemm_kernel<128, false, false><<<dim3(64, 6), 256, 0, stream>>>(
            X16, Wqkv16 + (size_t)l * 196608, tr_bqkv + l * 768, nullptr,
            S1, 8192, 768, 256);
        attn_kernel<<<256, 256, 0, stream>>>(S1, (unsigned int*)S2h);
        hgemm_kernel<64, false, false><<<dim3(64, 4), 256, 0, stream>>>(
            S2h, Wo16 + (size_t)l * 65536, tr_bo + l * 256, nullptr,
            CF32, 8192, 256, 256);
        add_ln_kernel<<<8192, 256, 0, stream>>>(X, CF32, tr_ln1_g + l * 256,
                                                tr_ln1_b + l * 256, X16);
        hgemm_kernel<128, true, true><<<dim3(64, 4), 256, 0, stream>>>(
            X16, Wff116 + (size_t)l * 131072, tr_ff_b1 + l * 512, nullptr,
            S1_16, 8192, 512, 256);
        hgemm_kernel<64, false, false><<<dim3(64, 4), 256, 0, stream>>>(
            S1_16, Wff216 + (size_t)l * 131072, tr_ff_b2 + l * 256, nullptr,
            CF32, 8192, 256, 512);
        add_ln_kernel<<<8192, 256, 0, stream>>>(X, CF32, tr_ln2_g + l * 256,
                                                tr_ln2_b + l * 256, X16);
    }

    // ---- pointer decode ----
    hgemm_kernel<64, false, false><<<dim3(64, 4), 256, 0, stream>>>(
        X16, WpW16, ptr_b, nullptr, EPROJ, 8192, 256, 256);
    gather_kernel<<<8192, 256, 0, stream>>>(X, target, Xg16);
    hgemm_kernel<128, false, false><<<dim3(64, 8), 256, 0, stream>>>(
        Xg16, Wih16, lstm_bih, lstm_bhh, S1, 8192, 1024, 256);
    lstm_kernel<<<32, 512, 0, stream>>>(S1, (const uint4*)WBf, HALL16);
    hgemm_kernel<64, false, false><<<dim3(64, 4), 256, 0, stream>>>(
        HALL16, WpW16, ptr_b, nullptr, CF32, 8192, 256, 256);
    pointer_kernel<<<dim3(16, 16, 32), 256, 0, stream>>>(CF32, EPROJ, ptr_v,
                                                         (float*)d_out);
}

// Round 6
// 1226.815 us; speedup vs baseline: 3.6436x; 1.2119x over previous
//
#include <hip/hip_runtime.h>
#include <cstddef>

#define DEV __device__ __forceinline__

DEV float fexp2(float x) { return __builtin_amdgcn_exp2f(x); }
DEV float frcp(float x)  { return __builtin_amdgcn_rcpf(x); }
DEV float fsigm(float x) { return frcp(1.0f + fexp2(-1.44269504f * x)); }
DEV float ftanh_(float x){ return 1.0f - 2.0f * frcp(1.0f + fexp2(2.88539008f * x)); }

typedef _Float16 h2t __attribute__((ext_vector_type(2)));
typedef _Float16 v8h __attribute__((ext_vector_type(8)));
typedef float v4f __attribute__((ext_vector_type(4)));
union U32H2 { unsigned int u; h2t h; };
DEV h2t u2h(unsigned int u) { U32H2 x; x.u = u; return x.h; }

// ---------------------------------------------------------------------------
// f16 MFMA GEMM: C[M,N] = A[M,K] @ W[N,K]^T + bias1 (+bias2); A,W f16 row-major
// BM=128, BK=32, 256 threads (4 waves 2x2), wave tile 64 x BN/2.
// ---------------------------------------------------------------------------
template <int BN, bool RELU, bool OUTF16>
__global__ __launch_bounds__(256) void hgemm_kernel(
    const _Float16* __restrict__ A, const _Float16* __restrict__ W,
    const float* __restrict__ bias1, const float* __restrict__ bias2,
    void* __restrict__ Cout, int M, int N, int K)
{
    constexpr int NT = BN / 32;
    constexpr int RB = BN / 64;
    __shared__ _Float16 As[128 * 32];
    __shared__ _Float16 Bs[BN * 32];

    const int tid = threadIdx.x;
    const int lane = tid & 63;
    const int lm = lane & 15, lq = lane >> 4;
    const int wrow = ((tid >> 6) & 1) * 64;
    const int wcol = (tid >> 7) * (BN / 2);
    const int m0 = blockIdx.x * 128, n0 = blockIdx.y * BN;
    const _Float16* Ab = A + (size_t)m0 * K;
    const _Float16* Wb = W + (size_t)n0 * K;

    v4f acc[4][NT];
#pragma unroll
    for (int i = 0; i < 4; ++i)
#pragma unroll
        for (int j = 0; j < NT; ++j) acc[i][j] = (v4f){0.f, 0.f, 0.f, 0.f};

    const int rowA0 = tid >> 2, qA0 = tid & 3;
    const int cc1 = 256 + tid, rowA1 = cc1 >> 2, qA1 = cc1 & 3;

    uint4 ra[2], rb[2];
    ra[0] = *(const uint4*)(Ab + (size_t)rowA0 * K + qA0 * 8);
    ra[1] = *(const uint4*)(Ab + (size_t)rowA1 * K + qA1 * 8);
    rb[0] = *(const uint4*)(Wb + (size_t)rowA0 * K + qA0 * 8);
    if (RB == 2) rb[1] = *(const uint4*)(Wb + (size_t)rowA1 * K + qA1 * 8);

    for (int k0 = 0; k0 < K; k0 += 32) {
        __syncthreads();
        *(uint4*)(As + (size_t)tid * 8) = ra[0];
        *(uint4*)(As + (size_t)(256 + tid) * 8) = ra[1];
        *(uint4*)(Bs + (size_t)tid * 8) = rb[0];
        if (RB == 2) *(uint4*)(Bs + (size_t)(256 + tid) * 8) = rb[1];
        __syncthreads();
        int kn = k0 + 32;
        if (kn < K) {
            ra[0] = *(const uint4*)(Ab + (size_t)rowA0 * K + kn + qA0 * 8);
            ra[1] = *(const uint4*)(Ab + (size_t)rowA1 * K + kn + qA1 * 8);
            rb[0] = *(const uint4*)(Wb + (size_t)rowA0 * K + kn + qA0 * 8);
            if (RB == 2) rb[1] = *(const uint4*)(Wb + (size_t)rowA1 * K + kn + qA1 * 8);
        }
        v8h af[4], bf[NT];
#pragma unroll
        for (int i = 0; i < 4; ++i)
            af[i] = *(const v8h*)(As + (size_t)(wrow + i * 16 + lm) * 32 + lq * 8);
#pragma unroll
        for (int j = 0; j < NT; ++j)
            bf[j] = *(const v8h*)(Bs + (size_t)(wcol + j * 16 + lm) * 32 + lq * 8);
#pragma unroll
        for (int i = 0; i < 4; ++i)
#pragma unroll
            for (int j = 0; j < NT; ++j)
                acc[i][j] = __builtin_amdgcn_mfma_f32_16x16x32_f16(
                    af[i], bf[j], acc[i][j], 0, 0, 0);
    }

#pragma unroll
    for (int j = 0; j < NT; ++j) {
        int col = n0 + wcol + j * 16 + lm;
        float bv = bias1[col];
        if (bias2) bv += bias2[col];
#pragma unroll
        for (int i = 0; i < 4; ++i) {
            int rbase = m0 + wrow + i * 16 + lq * 4;
#pragma unroll
            for (int rg = 0; rg < 4; ++rg) {
                float vv = acc[i][j][rg] + bv;
                if (RELU) vv = fmaxf(vv, 0.f);
                if (OUTF16)
                    ((_Float16*)Cout)[(size_t)(rbase + rg) * N + col] = (_Float16)vv;
                else
                    ((float*)Cout)[(size_t)(rbase + rg) * N + col] = vv;
            }
        }
    }
}

// ---------------------------------------------------------------------------
// Fused weight conversion: all 6 fp32 weight tensors -> one f16 blob.
// ---------------------------------------------------------------------------
__global__ __launch_bounds__(256) void cvt_all_kernel(
    const float* __restrict__ s0, const float* __restrict__ s1,
    const float* __restrict__ s2, const float* __restrict__ s3,
    const float* __restrict__ s4, const float* __restrict__ s5,
    _Float16* __restrict__ dst)
{
    int i = blockIdx.x * 256 + threadIdx.x;
    const float* src; int off;
    if (i < 589824)       { src = s0; off = 0; }
    else if (i < 786432)  { src = s1; off = 589824; }
    else if (i < 1179648) { src = s2; off = 786432; }
    else if (i < 1572864) { src = s3; off = 1179648; }
    else if (i < 1835008) { src = s4; off = 1572864; }
    else if (i < 1900544) { src = s5; off = 1835008; }
    else return;
    dst[i] = (_Float16)src[i - off];
}

// ---------------------------------------------------------------------------
__global__ __launch_bounds__(64) void bin_enc_kernel(
    const float* __restrict__ bin_info, const float* __restrict__ W1,
    const float* __restrict__ b1, const float* __restrict__ W2,
    const float* __restrict__ b2, float* __restrict__ BBo)
{
    int b = blockIdx.x, d = threadIdx.x;
    __shared__ float h1[64];
    float x0 = bin_info[b * 2], x1 = bin_info[b * 2 + 1];
    h1[d] = fmaxf(W1[d * 2] * x0 + W1[d * 2 + 1] * x1 + b1[d], 0.f);
    __syncthreads();
    float acc = b2[d];
#pragma unroll 4
    for (int e = 0; e < 64; ++e) acc += W2[d * 64 + e] * h1[e];
    BBo[b * 64 + d] = acc;
}

// ---------------------------------------------------------------------------
__global__ __launch_bounds__(128) void part_enc_kernel(
    const float* __restrict__ parts, const float* __restrict__ W1,
    const float* __restrict__ b1, const float* __restrict__ W2,
    const float* __restrict__ b2, const float* __restrict__ BBi,
    const float* __restrict__ pos_emb, float* __restrict__ X,
    _Float16* __restrict__ X16)
{
    __shared__ float W2s[128][129];
    __shared__ float h1[128];
    __shared__ float pin[16];
    int tid = threadIdx.x;
    int b = blockIdx.x >> 3, s0 = (blockIdx.x & 7) * 32;
    for (int l = 0; l < 128; ++l) W2s[l][tid] = W2[l * 128 + tid];
    float w1r[16];
#pragma unroll
    for (int k = 0; k < 16; ++k) w1r[k] = W1[tid * 16 + k];
    float bias1v = b1[tid], bias2v = b2[tid];
    for (int si = 0; si < 32; ++si) {
        int s = s0 + si;
        size_t row = (size_t)b * 256 + s;
        if (tid < 16) pin[tid] = parts[row * 16 + tid];
        __syncthreads();
        float h = bias1v;
#pragma unroll
        for (int k = 0; k < 16; ++k) h += w1r[k] * pin[k];
        h1[tid] = fmaxf(h, 0.f);
        __syncthreads();
        float acc = bias2v;
#pragma unroll 4
        for (int e = 0; e < 128; ++e) acc += W2s[tid][e] * h1[e];
        X[row * 256 + tid] = acc;
        X16[row * 256 + tid] = (_Float16)acc;
        if (tid < 64) {
            float bbv = BBi[b * 64 + tid];
            float pev = pos_emb[s * 64 + tid];
            X[row * 256 + 128 + tid] = bbv;
            X[row * 256 + 192 + tid] = pev;
            X16[row * 256 + 128 + tid] = (_Float16)bbv;
            X16[row * 256 + 192 + tid] = (_Float16)pev;
        }
        __syncthreads();
    }
}

// ---------------------------------------------------------------------------
// MFMA attention: one block per (b,h), 256 threads (4 waves).
// QKV f16 [8192][768]. Per wave: 4 row-strips of 16; per strip:
// 16 QK^T MFMAs -> row softmax (16-lane butterfly) -> P (normalized, f16)
// to per-wave LDS in A-layout -> 16 PV MFMAs with LDS V^T -> f16 out.
// ---------------------------------------------------------------------------
__global__ __launch_bounds__(256) void attn_mfma_kernel(
    const _Float16* __restrict__ QKV, _Float16* __restrict__ O16)
{
    int bh = blockIdx.x;
    int b = bh >> 3, h = bh & 7;
    const int tid = threadIdx.x;
    const int w = tid >> 6;
    const int lane = tid & 63;
    const int lm = lane & 15, lq = lane >> 4;
    const float c_se = 0.17677669529663687f * 1.44269504f;

    __shared__ _Float16 Ks[4][256][8];     // [k-chunk][n][8]
    __shared__ _Float16 Vt[32][264];       // V^T, padded
    __shared__ _Float16 Ps[4][16][264];    // per-wave P strip, padded

    const _Float16* qkvb = QKV + (size_t)(b * 256) * 768 + h * 32;
    {
        int s = tid;
        const _Float16* kr = qkvb + (size_t)s * 768 + 256;
#pragma unroll
        for (int c = 0; c < 4; ++c)
            *(uint4*)&Ks[c][s][0] = *(const uint4*)(kr + c * 8);
        const _Float16* vr = qkvb + (size_t)s * 768 + 512;
        _Float16 vtmp[32];
        *(uint4*)&vtmp[0]  = *(const uint4*)(vr);
        *(uint4*)&vtmp[8]  = *(const uint4*)(vr + 8);
        *(uint4*)&vtmp[16] = *(const uint4*)(vr + 16);
        *(uint4*)&vtmp[24] = *(const uint4*)(vr + 24);
#pragma unroll
        for (int d = 0; d < 32; ++d) Vt[d][s] = vtmp[d];
    }
    __syncthreads();

#pragma unroll 1
    for (int st = 0; st < 4; ++st) {
        int rt = w * 4 + st;
        v8h qf = *(const v8h*)(QKV + (size_t)(b * 256 + rt * 16 + lm) * 768
                               + h * 32 + lq * 8);
        v4f acc[16];
#pragma unroll
        for (int ct = 0; ct < 16; ++ct) {
            v8h kf = *(const v8h*)&Ks[lq][ct * 16 + lm][0];
            acc[ct] = __builtin_amdgcn_mfma_f32_16x16x32_f16(
                qf, kf, (v4f){0.f, 0.f, 0.f, 0.f}, 0, 0, 0);
        }
        float sminv[4];
#pragma unroll
        for (int r = 0; r < 4; ++r) {
            float m = acc[0][r];
#pragma unroll
            for (int ct = 1; ct < 16; ++ct) m = fmaxf(m, acc[ct][r]);
#pragma unroll
            for (int msk = 1; msk < 16; msk <<= 1)
                m = fmaxf(m, __shfl_xor(m, msk));
            float ssum = 0.f;
#pragma unroll
            for (int ct = 0; ct < 16; ++ct) {
                float e = fexp2((acc[ct][r] - m) * c_se);
                acc[ct][r] = e;
                ssum += e;
            }
#pragma unroll
            for (int msk = 1; msk < 16; msk <<= 1)
                ssum += __shfl_xor(ssum, msk);
            sminv[r] = frcp(ssum);
        }
#pragma unroll
        for (int ct = 0; ct < 16; ++ct)
#pragma unroll
            for (int r = 0; r < 4; ++r)
                Ps[w][lq * 4 + r][ct * 16 + lm] =
                    (_Float16)(acc[ct][r] * sminv[r]);
#pragma unroll
        for (int dt = 0; dt < 2; ++dt) {
            v4f o = (v4f){0.f, 0.f, 0.f, 0.f};
#pragma unroll
            for (int jc = 0; jc < 8; ++jc) {
                v8h pf = *(const v8h*)&Ps[w][lm][jc * 32 + lq * 8];
                v8h vf = *(const v8h*)&Vt[dt * 16 + lm][jc * 32 + lq * 8];
                o = __builtin_amdgcn_mfma_f32_16x16x32_f16(pf, vf, o, 0, 0, 0);
            }
#pragma unroll
            for (int r = 0; r < 4; ++r)
                O16[(size_t)(b * 256 + rt * 16 + lq * 4 + r) * 256
                    + h * 32 + dt * 16 + lm] = (_Float16)o[r];
        }
    }
}

// ---------------------------------------------------------------------------
// Residual add + LayerNorm, wave-per-row (no barriers). grid = rows/4.
// ---------------------------------------------------------------------------
__global__ __launch_bounds__(256) void add_ln_kernel(
    float* __restrict__ X, const float* __restrict__ R,
    const float* __restrict__ g, const float* __restrict__ beta,
    _Float16* __restrict__ X16)
{
    int row = blockIdx.x * 4 + (threadIdx.x >> 6);
    int lane = threadIdx.x & 63;
    size_t base = (size_t)row * 256 + lane * 4;
    float4 xv = *(const float4*)&X[base];
    float4 rv = *(const float4*)&R[base];
    float y0 = xv.x + rv.x, y1 = xv.y + rv.y;
    float y2 = xv.z + rv.z, y3 = xv.w + rv.w;
    float s = y0 + y1 + y2 + y3;
    float s2 = y0 * y0 + y1 * y1 + y2 * y2 + y3 * y3;
#pragma unroll
    for (int m = 1; m < 64; m <<= 1) {
        s += __shfl_xor(s, m);
        s2 += __shfl_xor(s2, m);
    }
    float mean = s * (1.f / 256.f);
    float var = s2 * (1.f / 256.f) - mean * mean;
    float inv = rsqrtf(var + 1e-5f);
    float4 gv = *(const float4*)&g[lane * 4];
    float4 bv = *(const float4*)&beta[lane * 4];
    float o0 = (y0 - mean) * inv * gv.x + bv.x;
    float o1 = (y1 - mean) * inv * gv.y + bv.y;
    float o2 = (y2 - mean) * inv * gv.z + bv.z;
    float o3 = (y3 - mean) * inv * gv.w + bv.w;
    *(float4*)&X[base] = make_float4(o0, o1, o2, o3);
    U32H2 a, c;
    a.h = h2t{(_Float16)o0, (_Float16)o1};
    c.h = h2t{(_Float16)o2, (_Float16)o3};
    uint2 u; u.x = a.u; u.y = c.u;
    *(uint2*)(X16 + base) = u;
}

// ---------------------------------------------------------------------------
__global__ __launch_bounds__(256) void gather_kernel(
    const float* __restrict__ X, const int* __restrict__ target,
    _Float16* __restrict__ Xg16)
{
    int row = blockIdx.x;
    int b = row >> 8, t = row & 255;
    int d = threadIdx.x;
    float val = 0.f;
    if (t > 0) {
        int src = target[b * 256 + t - 1];
        val = X[((size_t)b * 256 + src) * 256 + d];
    }
    Xg16[(size_t)row * 256 + d] = (_Float16)val;
}

// ---------------------------------------------------------------------------
// Whh fp32 [1024,256] -> f16x2 blob (R4 layout)
// ---------------------------------------------------------------------------
__global__ __launch_bounds__(256) void wcvt2_kernel(
    const float* __restrict__ Whh, unsigned int* __restrict__ WB)
{
    int idx = blockIdx.x * 256 + threadIdx.x;  // 0..131071
    int l = idx & 3;
    int gt = idx >> 2;
    int tid = gt & 511;
    int q = gt >> 9;                            // 0..63
    int i, c;
    if (q < 8)       { i = q >> 1; c = q & 1; }
    else if (q < 44) { int qq = q - 8; i = qq / 9; c = 2 + qq % 9; }
    else             { int qq = q - 44; c = 11 + (qq >> 2); i = qq & 3; }
    int r = ((tid & 255) << 2) + i;
    int k = ((tid >> 8) << 7) + (c << 3) + (l << 1);
    _Float16 lo = (_Float16)Whh[r * 256 + k];
    _Float16 hi = (_Float16)Whh[r * 256 + k + 1];
    U32H2 x; x.h = h2t{lo, hi};
    WB[idx] = x.u;
}

// ---------------------------------------------------------------------------
// LSTM recurrence (R4 structure): 1 block/batch, 512 threads,
// weights CU-local: 64 KB LDS + VGPR slab + 160 KB/step L2 stream.
// ---------------------------------------------------------------------------
__global__ __launch_bounds__(512) void lstm_kernel(
    const float* __restrict__ g_in, const uint4* __restrict__ WB4,
    _Float16* __restrict__ HALL16)
{
    const int b = blockIdx.x;
    const int tid = threadIdx.x;
    const int kh = tid >> 8, j4 = tid & 255;

    __shared__ uint4 WL4[4096];        // 64 KB
    __shared__ float gpart[2][1024];   // 8 KB
    __shared__ uint4 h2v[32];          // 512 B
    unsigned int* h2_s = (unsigned int*)h2v;

#pragma unroll
    for (int g = 0; g < 8; ++g) WL4[g * 512 + tid] = WB4[g * 512 + tid];
    uint4 wr[36];
#pragma unroll
    for (int q = 0; q < 36; ++q) wr[q] = WB4[(8 + q) * 512 + tid];
    if (tid < 128) h2_s[tid] = 0u;

    const float* ginb = g_in + (size_t)b * 256 * 1024;
    float gi0 = 0.f, gi1 = 0.f, gi2 = 0.f, gi3 = 0.f;
    if (tid < 256) {
        gi0 = ginb[tid];       gi1 = ginb[tid + 256];
        gi2 = ginb[tid + 512]; gi3 = ginb[tid + 768];
    }
    float c_state = 0.f;
    const uint4* SW4 = WB4 + 44 * 512;
    __syncthreads();

    for (int t = 0; t < 256; ++t) {
        uint4 sw[20];
#pragma unroll
        for (int q = 0; q < 8; ++q) sw[q] = SW4[q * 512 + tid];

        float acc[4] = {0.f, 0.f, 0.f, 0.f};
#pragma unroll
        for (int c = 0; c < 16; ++c) {
            if (c == 4) {
#pragma unroll
                for (int q = 8; q < 20; ++q) sw[q] = SW4[q * 512 + tid];
            }
            uint4 h4 = h2v[(kh << 4) + c];
            h2t hx = u2h(h4.x), hy = u2h(h4.y), hz = u2h(h4.z), hw = u2h(h4.w);
#pragma unroll
            for (int i = 0; i < 4; ++i) {
                uint4 w = (c < 2)  ? WL4[((i << 1) + c) * 512 + tid]
                        : (c < 11) ? wr[i * 9 + (c - 2)]
                                   : sw[((c - 11) << 2) + i];
                acc[i] = __builtin_amdgcn_fdot2(u2h(w.x), hx, acc[i], false);
                acc[i] = __builtin_amdgcn_fdot2(u2h(w.y), hy, acc[i], false);
                acc[i] = __builtin_amdgcn_fdot2(u2h(w.z), hz, acc[i], false);
                acc[i] = __builtin_amdgcn_fdot2(u2h(w.w), hw, acc[i], false);
            }
        }
        *(float4*)&gpart[kh][j4 << 2] = make_float4(acc[0], acc[1], acc[2], acc[3]);
        __syncthreads();

        if (tid < 256) {
            int j = tid;
            float ig = gi0 + gpart[0][j]       + gpart[1][j];
            float fg = gi1 + gpart[0][j + 256] + gpart[1][j + 256];
            float gg = gi2 + gpart[0][j + 512] + gpart[1][j + 512];
            float og = gi3 + gpart[0][j + 768] + gpart[1][j + 768];
            c_state = fsigm(fg) * c_state + fsigm(ig) * ftanh_(gg);
            float h = fsigm(og) * ftanh_(c_state);
            HALL16[((size_t)(b * 256 + t)) * 256 + j] = (_Float16)h;
            U32H2 hxp; hxp.h = h2t{(_Float16)h, (_Float16)0.f};
            unsigned int hu = hxp.u & 0xffffu;
            unsigned int other = (unsigned int)__shfl_xor((int)hu, 1);
            if ((j & 1) == 0) h2_s[j >> 1] = hu | (other << 16);
            int tn = (t < 255) ? (t + 1) : 255;
            const float* gnext = ginb + (size_t)tn * 1024;
            gi0 = gnext[j];       gi1 = gnext[j + 256];
            gi2 = gnext[j + 512]; gi3 = gnext[j + 768];
        }
        __syncthreads();
    }
}

// ---------------------------------------------------------------------------
__global__ __launch_bounds__(256) void pointer_kernel(
    const float* __restrict__ HP, const float* __restrict__ EP,
    const float* __restrict__ v, float* __restrict__ out)
{
    int b = blockIdx.z, tt = blockIdx.y, it = blockIdx.x;
    __shared__ float hp_s[16][260];
    __shared__ float ep_s[16][260];
    __shared__ float v_s[256];
    int tid = threadIdx.x;
    const float* hpb = HP + ((size_t)b * 256 + tt * 16) * 256;
    const float* epb = EP + ((size_t)b * 256 + it * 16) * 256;
#pragma unroll
    for (int l = 0; l < 4; ++l) {
        int idx = tid + l * 256;
        int r = idx >> 6, c4 = idx & 63;
        float4 hv = *(const float4*)(hpb + r * 256 + c4 * 4);
        *(float4*)&hp_s[r][c4 * 4] = hv;
        float4 ev = *(const float4*)(epb + r * 256 + c4 * 4);
        *(float4*)&ep_s[r][c4 * 4] = ev;
    }
    v_s[tid] = v[tid];
    __syncthreads();
    int tl = tid >> 4, il = tid & 15;
    float acc = 0.f;
#pragma unroll 4
    for (int d = 0; d < 256; ++d)
        acc += v_s[d] * ftanh_(hp_s[tl][d] + ep_s[il][d]);
    out[((size_t)b * 256 + tt * 16 + tl) * 256 + it * 16 + il] = acc;
}

// ---------------------------------------------------------------------------
extern "C" void kernel_launch(void* const* d_in, const int* in_sizes, int n_in,
                              void* d_out, int out_size, void* d_ws, size_t ws_size,
                              hipStream_t stream)
{
    const float* parts    = (const float*)d_in[0];
    const float* bin_info = (const float*)d_in[1];
    const int*   target   = (const int*)d_in[2];
    const float* pe_W1 = (const float*)d_in[3];
    const float* pe_b1 = (const float*)d_in[4];
    const float* pe_W2 = (const float*)d_in[5];
    const float* pe_b2 = (const float*)d_in[6];
    const float* be_W1 = (const float*)d_in[7];
    const float* be_b1 = (const float*)d_in[8];
    const float* be_W2 = (const float*)d_in[9];
    const float* be_b2 = (const float*)d_in[10];
    const float* pos_emb = (const float*)d_in[11];
    const float* tr_Wqkv = (const float*)d_in[12];
    const float* tr_bqkv = (const float*)d_in[13];
    const float* tr_Wo   = (const float*)d_in[14];
    const float* tr_bo   = (const float*)d_in[15];
    const float* tr_ln1_g = (const float*)d_in[16];
    const float* tr_ln1_b = (const float*)d_in[17];
    const float* tr_ff_W1 = (const float*)d_in[18];
    const float* tr_ff_b1 = (const float*)d_in[19];
    const float* tr_ff_W2 = (const float*)d_in[20];
    const float* tr_ff_b2 = (const float*)d_in[21];
    const float* tr_ln2_g = (const float*)d_in[22];
    const float* tr_ln2_b = (const float*)d_in[23];
    const float* lstm_Wih = (const float*)d_in[24];
    const float* lstm_Whh = (const float*)d_in[25];
    const float* lstm_bih = (const float*)d_in[26];
    const float* lstm_bhh = (const float*)d_in[27];
    const float* ptr_W = (const float*)d_in[28];
    const float* ptr_b = (const float*)d_in[29];
    const float* ptr_v = (const float*)d_in[30];

    // ---- workspace layout (floats) ----
    float* ws = (float*)d_ws;
    float* X     = ws;                        // 2,097,152
    float* S1    = X + 2097152;               // 8,388,608 (qkv f16 / ff1 f16 / g_in f32)
    float* CF32  = S1 + 8388608;              // 2,097,152 (Wo/ff2 out, later HP)
    float* EPROJ = CF32 + 2097152;            // 2,097,152
    float* X16f  = EPROJ + 2097152;           // 1,048,576 (X16; later Xg16)
    float* S2f   = X16f + 1048576;            // 1,048,576 (attn out f16; later HALL16)
    float* W16f  = S2f + 1048576;             // 1,048,576 (f16 weight blob)
    float* WBf   = W16f + 1048576;            // 131,072 (lstm Whh blob)
    float* BBuf  = WBf + 131072;              // 2,048

    _Float16* X16    = (_Float16*)X16f;
    _Float16* Xg16   = X16;
    _Float16* S2h    = (_Float16*)S2f;
    _Float16* HALL16 = S2h;
    _Float16* S1h    = (_Float16*)S1;         // qkv f16 out / ff1 f16 out
    _Float16* W16    = (_Float16*)W16f;
    _Float16* Wqkv16 = W16;                   // 589,824
    _Float16* Wo16   = Wqkv16 + 589824;       // 196,608
    _Float16* Wff116 = Wo16 + 196608;         // 393,216
    _Float16* Wff216 = Wff116 + 393216;       // 393,216
    _Float16* Wih16  = Wff216 + 393216;       // 262,144
    _Float16* WpW16  = Wih16 + 262144;        // 65,536

    // ---- one-time weight conversions (fused) ----
    cvt_all_kernel<<<7424, 256, 0, stream>>>(tr_Wqkv, tr_Wo, tr_ff_W1, tr_ff_W2,
                                             lstm_Wih, ptr_W, W16);
    wcvt2_kernel<<<512, 256, 0, stream>>>(lstm_Whh, (unsigned int*)WBf);

    // ---- encoders ----
    bin_enc_kernel<<<32, 64, 0, stream>>>(bin_info, be_W1, be_b1, be_W2, be_b2, BBuf);
    part_enc_kernel<<<256, 128, 0, stream>>>(parts, pe_W1, pe_b1, pe_W2, pe_b2,
                                             BBuf, pos_emb, X, X16);

    // ---- transformer layers ----
    for (int l = 0; l < 3; ++l) {
        hgemm_kernel<128, false, true><<<dim3(64, 6), 256, 0, stream>>>(
            X16, Wqkv16 + (size_t)l * 196608, tr_bqkv + l * 768, nullptr,
            S1h, 8192, 768, 256);
        attn_mfma_kernel<<<256, 256, 0, stream>>>(S1h, S2h);
        hgemm_kernel<64, false, false><<<dim3(64, 4), 256, 0, stream>>>(
            S2h, Wo16 + (size_t)l * 65536, tr_bo + l * 256, nullptr,
            CF32, 8192, 256, 256);
        add_ln_kernel<<<2048, 256, 0, stream>>>(X, CF32, tr_ln1_g + l * 256,
                                                tr_ln1_b + l * 256, X16);
        hgemm_kernel<128, true, true><<<dim3(64, 4), 256, 0, stream>>>(
            X16, Wff116 + (size_t)l * 131072, tr_ff_b1 + l * 512, nullptr,
            S1h, 8192, 512, 256);
        hgemm_kernel<64, false, false><<<dim3(64, 4), 256, 0, stream>>>(
            S1h, Wff216 + (size_t)l * 131072, tr_ff_b2 + l * 256, nullptr,
            CF32, 8192, 256, 512);
        add_ln_kernel<<<2048, 256, 0, stream>>>(X, CF32, tr_ln2_g + l * 256,
                                                tr_ln2_b + l * 256, X16);
    }

    // ---- pointer decode ----
    hgemm_kernel<64, false, false><<<dim3(64, 4), 256, 0, stream>>>(
        X16, WpW16, ptr_b, nullptr, EPROJ, 8192, 256, 256);
    gather_kernel<<<8192, 256, 0, stream>>>(X, target, Xg16);
    hgemm_kernel<128, false, false><<<dim3(64, 8), 256, 0, stream>>>(
        Xg16, Wih16, lstm_bih, lstm_bhh, S1, 8192, 1024, 256);
    lstm_kernel<<<32, 512, 0, stream>>>(S1, (const uint4*)WBf, HALL16);
    hgemm_kernel<64, false, false><<<dim3(64, 4), 256, 0, stream>>>(
        HALL16, WpW16, ptr_b, nullptr, CF32, 8192, 256, 256);
    pointer_kernel<<<dim3(16, 16, 32), 256, 0, stream>>>(CF32, EPROJ, ptr_v,
                                                         (float*)d_out);
}

// Round 7
// 966.119 us; speedup vs baseline: 4.6268x; 1.2698x over previous
//
#include <hip/hip_runtime.h>
#include <cstddef>

#define DEV __device__ __forceinline__

DEV float fexp2(float x) { return __builtin_amdgcn_exp2f(x); }
DEV float frcp(float x)  { return __builtin_amdgcn_rcpf(x); }
DEV float fsigm(float x) { return frcp(1.0f + fexp2(-1.44269504f * x)); }
DEV float ftanh_(float x){ return 1.0f - 2.0f * frcp(1.0f + fexp2(2.88539008f * x)); }

typedef _Float16 h2t __attribute__((ext_vector_type(2)));
typedef _Float16 v8h __attribute__((ext_vector_type(8)));
typedef float v4f __attribute__((ext_vector_type(4)));
union U32H2 { unsigned int u; h2t h; };
DEV h2t u2h(unsigned int u) { U32H2 x; x.u = u; return x.h; }

// ---------------------------------------------------------------------------
// f16 MFMA GEMM: C[M,N] = A[M,K] @ W[N,K]^T + bias; A,W f16 row-major.
// BM in {64,128}, BK=32, 256 threads (4 waves, 2x2), wave tile (BM/2)x(BN/2).
// ---------------------------------------------------------------------------
template <int BM, int BN, bool RELU, bool OUTF16>
__global__ __launch_bounds__(256) void hgemm_kernel(
    const _Float16* __restrict__ A, const _Float16* __restrict__ W,
    const float* __restrict__ bias1, const float* __restrict__ bias2,
    void* __restrict__ Cout, int M, int N, int K)
{
    constexpr int MT = BM / 32;
    constexpr int NT = BN / 32;
    constexpr int RA = BM / 64;
    constexpr int RB = BN / 64;
    __shared__ _Float16 As[BM * 32];
    __shared__ _Float16 Bs[BN * 32];

    const int tid = threadIdx.x;
    const int lane = tid & 63;
    const int lm = lane & 15, lq = lane >> 4;
    const int wrow = ((tid >> 6) & 1) * (BM / 2);
    const int wcol = (tid >> 7) * (BN / 2);
    const int m0 = blockIdx.x * BM, n0 = blockIdx.y * BN;
    const _Float16* Ab = A + (size_t)m0 * K;
    const _Float16* Wb = W + (size_t)n0 * K;

    v4f acc[MT][NT];
#pragma unroll
    for (int i = 0; i < MT; ++i)
#pragma unroll
        for (int j = 0; j < NT; ++j) acc[i][j] = (v4f){0.f, 0.f, 0.f, 0.f};

    const int rowS = tid >> 2, qS = tid & 3;

    uint4 ra[RA], rb[RB];
#pragma unroll
    for (int r = 0; r < RA; ++r)
        ra[r] = *(const uint4*)(Ab + (size_t)(rowS + 64 * r) * K + qS * 8);
#pragma unroll
    for (int r = 0; r < RB; ++r)
        rb[r] = *(const uint4*)(Wb + (size_t)(rowS + 64 * r) * K + qS * 8);

    for (int k0 = 0; k0 < K; k0 += 32) {
        __syncthreads();
#pragma unroll
        for (int r = 0; r < RA; ++r)
            *(uint4*)(As + (size_t)(tid + 256 * r) * 8) = ra[r];
#pragma unroll
        for (int r = 0; r < RB; ++r)
            *(uint4*)(Bs + (size_t)(tid + 256 * r) * 8) = rb[r];
        __syncthreads();
        int kn = k0 + 32;
        if (kn < K) {
#pragma unroll
            for (int r = 0; r < RA; ++r)
                ra[r] = *(const uint4*)(Ab + (size_t)(rowS + 64 * r) * K + kn + qS * 8);
#pragma unroll
            for (int r = 0; r < RB; ++r)
                rb[r] = *(const uint4*)(Wb + (size_t)(rowS + 64 * r) * K + kn + qS * 8);
        }
        v8h af[MT], bf[NT];
#pragma unroll
        for (int i = 0; i < MT; ++i)
            af[i] = *(const v8h*)(As + (size_t)(wrow + i * 16 + lm) * 32 + lq * 8);
#pragma unroll
        for (int j = 0; j < NT; ++j)
            bf[j] = *(const v8h*)(Bs + (size_t)(wcol + j * 16 + lm) * 32 + lq * 8);
#pragma unroll
        for (int i = 0; i < MT; ++i)
#pragma unroll
            for (int j = 0; j < NT; ++j)
                acc[i][j] = __builtin_amdgcn_mfma_f32_16x16x32_f16(
                    af[i], bf[j], acc[i][j], 0, 0, 0);
    }

#pragma unroll
    for (int j = 0; j < NT; ++j) {
        int col = n0 + wcol + j * 16 + lm;
        float bv = bias1[col];
        if (bias2) bv += bias2[col];
#pragma unroll
        for (int i = 0; i < MT; ++i) {
            int rbase = m0 + wrow + i * 16 + lq * 4;
#pragma unroll
            for (int rg = 0; rg < 4; ++rg) {
                float vv = acc[i][j][rg] + bv;
                if (RELU) vv = fmaxf(vv, 0.f);
                if (OUTF16)
                    ((_Float16*)Cout)[(size_t)(rbase + rg) * N + col] = (_Float16)vv;
                else
                    ((float*)Cout)[(size_t)(rbase + rg) * N + col] = vv;
            }
        }
    }
}

// ---------------------------------------------------------------------------
// Fused weight conversion. Wih dest rows are gate-interleaved: dest row
// j*4+g = src row g*256+j (so lstm g_in ends up [t][j*4+g]).
// ---------------------------------------------------------------------------
__global__ __launch_bounds__(256) void cvt_all_kernel(
    const float* __restrict__ s0, const float* __restrict__ s1,
    const float* __restrict__ s2, const float* __restrict__ s3,
    const float* __restrict__ s4, const float* __restrict__ s5,
    _Float16* __restrict__ dst)
{
    int i = blockIdx.x * 256 + threadIdx.x;
    if (i >= 1900544) return;
    float val;
    if (i < 589824)       val = s0[i];
    else if (i < 786432)  val = s1[i - 589824];
    else if (i < 1179648) val = s2[i - 786432];
    else if (i < 1572864) val = s3[i - 1179648];
    else if (i < 1835008) {
        int idx = i - 1572864;
        int rp = idx >> 8, k = idx & 255;
        int j = rp >> 2, g = rp & 3;
        val = s4[(g * 256 + j) * 256 + k];
    }
    else                  val = s5[i - 1835008];
    dst[i] = (_Float16)val;
}

// ---------------------------------------------------------------------------
__global__ __launch_bounds__(64) void bin_enc_kernel(
    const float* __restrict__ bin_info, const float* __restrict__ W1,
    const float* __restrict__ b1, const float* __restrict__ W2,
    const float* __restrict__ b2, float* __restrict__ BBo)
{
    int b = blockIdx.x, d = threadIdx.x;
    __shared__ float h1[64];
    float x0 = bin_info[b * 2], x1 = bin_info[b * 2 + 1];
    h1[d] = fmaxf(W1[d * 2] * x0 + W1[d * 2 + 1] * x1 + b1[d], 0.f);
    __syncthreads();
    float acc = b2[d];
#pragma unroll 4
    for (int e = 0; e < 64; ++e) acc += W2[d * 64 + e] * h1[e];
    BBo[b * 64 + d] = acc;
}

// ---------------------------------------------------------------------------
__global__ __launch_bounds__(128) void part_enc_kernel(
    const float* __restrict__ parts, const float* __restrict__ W1,
    const float* __restrict__ b1, const float* __restrict__ W2,
    const float* __restrict__ b2, const float* __restrict__ BBi,
    const float* __restrict__ pos_emb, float* __restrict__ X,
    _Float16* __restrict__ X16)
{
    __shared__ float W2s[128][129];
    __shared__ float h1[128];
    __shared__ float pin[16];
    int tid = threadIdx.x;
    int b = blockIdx.x >> 3, s0 = (blockIdx.x & 7) * 32;
    for (int l = 0; l < 128; ++l) W2s[l][tid] = W2[l * 128 + tid];
    float w1r[16];
#pragma unroll
    for (int k = 0; k < 16; ++k) w1r[k] = W1[tid * 16 + k];
    float bias1v = b1[tid], bias2v = b2[tid];
    for (int si = 0; si < 32; ++si) {
        int s = s0 + si;
        size_t row = (size_t)b * 256 + s;
        if (tid < 16) pin[tid] = parts[row * 16 + tid];
        __syncthreads();
        float h = bias1v;
#pragma unroll
        for (int k = 0; k < 16; ++k) h += w1r[k] * pin[k];
        h1[tid] = fmaxf(h, 0.f);
        __syncthreads();
        float acc = bias2v;
#pragma unroll 4
        for (int e = 0; e < 128; ++e) acc += W2s[tid][e] * h1[e];
        X[row * 256 + tid] = acc;
        X16[row * 256 + tid] = (_Float16)acc;
        if (tid < 64) {
            float bbv = BBi[b * 64 + tid];
            float pev = pos_emb[s * 64 + tid];
            X[row * 256 + 128 + tid] = bbv;
            X[row * 256 + 192 + tid] = pev;
            X16[row * 256 + 128 + tid] = (_Float16)bbv;
            X16[row * 256 + 192 + tid] = (_Float16)pev;
        }
        __syncthreads();
    }
}

// ---------------------------------------------------------------------------
// MFMA attention: one block per (b,h), 256 threads (4 waves).
// ---------------------------------------------------------------------------
__global__ __launch_bounds__(256) void attn_mfma_kernel(
    const _Float16* __restrict__ QKV, _Float16* __restrict__ O16)
{
    int bh = blockIdx.x;
    int b = bh >> 3, h = bh & 7;
    const int tid = threadIdx.x;
    const int w = tid >> 6;
    const int lane = tid & 63;
    const int lm = lane & 15, lq = lane >> 4;
    const float c_se = 0.17677669529663687f * 1.44269504f;

    __shared__ _Float16 Ks[4][256][8];
    __shared__ _Float16 Vt[32][264];
    __shared__ _Float16 Ps[4][16][264];

    const _Float16* qkvb = QKV + (size_t)(b * 256) * 768 + h * 32;
    {
        int s = tid;
        const _Float16* kr = qkvb + (size_t)s * 768 + 256;
#pragma unroll
        for (int c = 0; c < 4; ++c)
            *(uint4*)&Ks[c][s][0] = *(const uint4*)(kr + c * 8);
        const _Float16* vr = qkvb + (size_t)s * 768 + 512;
        _Float16 vtmp[32];
        *(uint4*)&vtmp[0]  = *(const uint4*)(vr);
        *(uint4*)&vtmp[8]  = *(const uint4*)(vr + 8);
        *(uint4*)&vtmp[16] = *(const uint4*)(vr + 16);
        *(uint4*)&vtmp[24] = *(const uint4*)(vr + 24);
#pragma unroll
        for (int d = 0; d < 32; ++d) Vt[d][s] = vtmp[d];
    }
    __syncthreads();

#pragma unroll 1
    for (int st = 0; st < 4; ++st) {
        int rt = w * 4 + st;
        v8h qf = *(const v8h*)(QKV + (size_t)(b * 256 + rt * 16 + lm) * 768
                               + h * 32 + lq * 8);
        v4f acc[16];
#pragma unroll
        for (int ct = 0; ct < 16; ++ct) {
            v8h kf = *(const v8h*)&Ks[lq][ct * 16 + lm][0];
            acc[ct] = __builtin_amdgcn_mfma_f32_16x16x32_f16(
                qf, kf, (v4f){0.f, 0.f, 0.f, 0.f}, 0, 0, 0);
        }
        float sminv[4];
#pragma unroll
        for (int r = 0; r < 4; ++r) {
            float m = acc[0][r];
#pragma unroll
            for (int ct = 1; ct < 16; ++ct) m = fmaxf(m, acc[ct][r]);
#pragma unroll
            for (int msk = 1; msk < 16; msk <<= 1)
                m = fmaxf(m, __shfl_xor(m, msk));
            float ssum = 0.f;
#pragma unroll
            for (int ct = 0; ct < 16; ++ct) {
                float e = fexp2((acc[ct][r] - m) * c_se);
                acc[ct][r] = e;
                ssum += e;
            }
#pragma unroll
            for (int msk = 1; msk < 16; msk <<= 1)
                ssum += __shfl_xor(ssum, msk);
            sminv[r] = frcp(ssum);
        }
#pragma unroll
        for (int ct = 0; ct < 16; ++ct)
#pragma unroll
            for (int r = 0; r < 4; ++r)
                Ps[w][lq * 4 + r][ct * 16 + lm] =
                    (_Float16)(acc[ct][r] * sminv[r]);
#pragma unroll
        for (int dt = 0; dt < 2; ++dt) {
            v4f o = (v4f){0.f, 0.f, 0.f, 0.f};
#pragma unroll
            for (int jc = 0; jc < 8; ++jc) {
                v8h pf = *(const v8h*)&Ps[w][lm][jc * 32 + lq * 8];
                v8h vf = *(const v8h*)&Vt[dt * 16 + lm][jc * 32 + lq * 8];
                o = __builtin_amdgcn_mfma_f32_16x16x32_f16(pf, vf, o, 0, 0, 0);
            }
#pragma unroll
            for (int r = 0; r < 4; ++r)
                O16[(size_t)(b * 256 + rt * 16 + lq * 4 + r) * 256
                    + h * 32 + dt * 16 + lm] = (_Float16)o[r];
        }
    }
}

// ---------------------------------------------------------------------------
// Residual add + LayerNorm, wave-per-row. grid = rows/4.
// ---------------------------------------------------------------------------
__global__ __launch_bounds__(256) void add_ln_kernel(
    float* __restrict__ X, const float* __restrict__ R,
    const float* __restrict__ g, const float* __restrict__ beta,
    _Float16* __restrict__ X16)
{
    int row = blockIdx.x * 4 + (threadIdx.x >> 6);
    int lane = threadIdx.x & 63;
    size_t base = (size_t)row * 256 + lane * 4;
    float4 xv = *(const float4*)&X[base];
    float4 rv = *(const float4*)&R[base];
    float y0 = xv.x + rv.x, y1 = xv.y + rv.y;
    float y2 = xv.z + rv.z, y3 = xv.w + rv.w;
    float s = y0 + y1 + y2 + y3;
    float s2 = y0 * y0 + y1 * y1 + y2 * y2 + y3 * y3;
#pragma unroll
    for (int m = 1; m < 64; m <<= 1) {
        s += __shfl_xor(s, m);
        s2 += __shfl_xor(s2, m);
    }
    float mean = s * (1.f / 256.f);
    float var = s2 * (1.f / 256.f) - mean * mean;
    float inv = rsqrtf(var + 1e-5f);
    float4 gv = *(const float4*)&g[lane * 4];
    float4 bv = *(const float4*)&beta[lane * 4];
    float o0 = (y0 - mean) * inv * gv.x + bv.x;
    float o1 = (y1 - mean) * inv * gv.y + bv.y;
    float o2 = (y2 - mean) * inv * gv.z + bv.z;
    float o3 = (y3 - mean) * inv * gv.w + bv.w;
    *(float4*)&X[base] = make_float4(o0, o1, o2, o3);
    U32H2 a, c;
    a.h = h2t{(_Float16)o0, (_Float16)o1};
    c.h = h2t{(_Float16)o2, (_Float16)o3};
    uint2 u; u.x = a.u; u.y = c.u;
    *(uint2*)(X16 + base) = u;
}

// ---------------------------------------------------------------------------
__global__ __launch_bounds__(256) void gather_kernel(
    const float* __restrict__ X, const int* __restrict__ target,
    _Float16* __restrict__ Xg16)
{
    int row = blockIdx.x;
    int b = row >> 8, t = row & 255;
    int d = threadIdx.x;
    float val = 0.f;
    if (t > 0) {
        int src = target[b * 256 + t - 1];
        val = X[((size_t)b * 256 + src) * 256 + d];
    }
    Xg16[(size_t)row * 256 + d] = (_Float16)val;
}

// ---------------------------------------------------------------------------
// Whh fp32 [1024,256] -> f16x2 blob; split: LDS 8 words (c<2), regs 44
// (2<=c<13), stream 12 (13<=c<16). Also builds permuted lstm bias PB.
// ---------------------------------------------------------------------------
__global__ __launch_bounds__(256) void wcvt2_kernel(
    const float* __restrict__ Whh, unsigned int* __restrict__ WB,
    const float* __restrict__ bih, const float* __restrict__ bhh,
    float* __restrict__ PB)
{
    int idx = blockIdx.x * 256 + threadIdx.x;  // 0..131071
    if (idx < 1024) {
        int j = idx >> 2, g = idx & 3;
        PB[idx] = bih[g * 256 + j] + bhh[g * 256 + j];
    }
    int l = idx & 3;
    int gt = idx >> 2;
    int tid = gt & 511;
    int q = gt >> 9;                            // 0..63
    int i, c;
    if (q < 8)       { i = q >> 1; c = q & 1; }
    else if (q < 52) { int qq = q - 8; i = qq / 11; c = 2 + qq % 11; }
    else             { int qq = q - 52; c = 13 + (qq >> 2); i = qq & 3; }
    int r = ((tid & 255) << 2) + i;
    int k = ((tid >> 8) << 7) + (c << 3) + (l << 1);
    _Float16 lo = (_Float16)Whh[r * 256 + k];
    _Float16 hi = (_Float16)Whh[r * 256 + k + 1];
    U32H2 x; x.h = h2t{lo, hi};
    WB[idx] = x.u;
}

// ---------------------------------------------------------------------------
// LSTM recurrence: 1 block/batch, 512 threads. Weights: 64 KB LDS +
// 176 VGPR slab + 96 KB/step L2 stream. g_in f16 gate-interleaved [t][j*4+g].
// ---------------------------------------------------------------------------
__global__ __launch_bounds__(512) void lstm_kernel(
    const _Float16* __restrict__ g_in, const uint4* __restrict__ WB4,
    _Float16* __restrict__ HALL16)
{
    const int b = blockIdx.x;
    const int tid = threadIdx.x;
    const int kh = tid >> 8, j4 = tid & 255;

    __shared__ uint4 WL4[4096];        // 64 KB
    __shared__ float gpart[2][1024];   // 8 KB
    __shared__ uint4 h2v[32];          // 512 B
    unsigned int* h2_s = (unsigned int*)h2v;

#pragma unroll
    for (int g = 0; g < 8; ++g) WL4[g * 512 + tid] = WB4[g * 512 + tid];
    uint4 wr[44];
#pragma unroll
    for (int q = 0; q < 44; ++q) wr[q] = WB4[(8 + q) * 512 + tid];
    if (tid < 128) h2_s[tid] = 0u;

    const _Float16* ginb = g_in + (size_t)b * 256 * 1024;
    uint2 gi = make_uint2(0u, 0u);
    if (tid < 256) gi = *(const uint2*)(ginb + tid * 4);
    float c_state = 0.f;
    const uint4* SW4 = WB4 + 52 * 512;
    __syncthreads();

    for (int t = 0; t < 256; ++t) {
        uint4 sw[12];
#pragma unroll
        for (int q = 0; q < 4; ++q) sw[q] = SW4[q * 512 + tid];

        float acc[4] = {0.f, 0.f, 0.f, 0.f};
#pragma unroll
        for (int c = 0; c < 16; ++c) {
            if (c == 2) {
#pragma unroll
                for (int q = 4; q < 8; ++q) sw[q] = SW4[q * 512 + tid];
            }
            if (c == 6) {
#pragma unroll
                for (int q = 8; q < 12; ++q) sw[q] = SW4[q * 512 + tid];
            }
            uint4 h4 = h2v[(kh << 4) + c];
            h2t hx = u2h(h4.x), hy = u2h(h4.y), hz = u2h(h4.z), hw = u2h(h4.w);
#pragma unroll
            for (int i = 0; i < 4; ++i) {
                uint4 w = (c < 2)  ? WL4[((i << 1) + c) * 512 + tid]
                        : (c < 13) ? wr[i * 11 + (c - 2)]
                                   : sw[((c - 13) << 2) + i];
                acc[i] = __builtin_amdgcn_fdot2(u2h(w.x), hx, acc[i], false);
                acc[i] = __builtin_amdgcn_fdot2(u2h(w.y), hy, acc[i], false);
                acc[i] = __builtin_amdgcn_fdot2(u2h(w.z), hz, acc[i], false);
                acc[i] = __builtin_amdgcn_fdot2(u2h(w.w), hw, acc[i], false);
            }
        }
        *(float4*)&gpart[kh][j4 << 2] = make_float4(acc[0], acc[1], acc[2], acc[3]);
        __syncthreads();

        if (tid < 256) {
            int j = tid;
            h2t p0 = u2h(gi.x), p1 = u2h(gi.y);
            float ig = (float)p0.x + gpart[0][j]       + gpart[1][j];
            float fg = (float)p0.y + gpart[0][j + 256] + gpart[1][j + 256];
            float gg = (float)p1.x + gpart[0][j + 512] + gpart[1][j + 512];
            float og = (float)p1.y + gpart[0][j + 768] + gpart[1][j + 768];
            c_state = fsigm(fg) * c_state + fsigm(ig) * ftanh_(gg);
            float h = fsigm(og) * ftanh_(c_state);
            HALL16[((size_t)(b * 256 + t)) * 256 + j] = (_Float16)h;
            U32H2 hxp; hxp.h = h2t{(_Float16)h, (_Float16)0.f};
            unsigned int hu = hxp.u & 0xffffu;
            unsigned int other = (unsigned int)__shfl_xor((int)hu, 1);
            if ((j & 1) == 0) h2_s[j >> 1] = hu | (other << 16);
            int tn = (t < 255) ? (t + 1) : 255;
            gi = *(const uint2*)(ginb + (size_t)tn * 1024 + j * 4);
        }
        __syncthreads();
    }
}

// ---------------------------------------------------------------------------
// Pointer logits: out[b,t,i] = vsum - 2 * sum_d v_d / (1 + exp2(s_d)),
// s = 2.88539*(hp+ep) (scale folded into LDS staging).
// ---------------------------------------------------------------------------
__global__ __launch_bounds__(256) void pointer_kernel(
    const float* __restrict__ HP, const float* __restrict__ EP,
    const float* __restrict__ v, float* __restrict__ out)
{
    int b = blockIdx.z, tt = blockIdx.y, it = blockIdx.x;
    __shared__ float hp_s[16][260];
    __shared__ float ep_s[16][260];
    __shared__ float v_s[256];
    __shared__ float red[4];
    int tid = threadIdx.x;
    const float cs = 2.88539008f;
    const float* hpb = HP + ((size_t)b * 256 + tt * 16) * 256;
    const float* epb = EP + ((size_t)b * 256 + it * 16) * 256;
#pragma unroll
    for (int l = 0; l < 4; ++l) {
        int idx = tid + l * 256;
        int r = idx >> 6, c4 = idx & 63;
        float4 hv = *(const float4*)(hpb + r * 256 + c4 * 4);
        hv.x *= cs; hv.y *= cs; hv.z *= cs; hv.w *= cs;
        *(float4*)&hp_s[r][c4 * 4] = hv;
        float4 ev = *(const float4*)(epb + r * 256 + c4 * 4);
        ev.x *= cs; ev.y *= cs; ev.z *= cs; ev.w *= cs;
        *(float4*)&ep_s[r][c4 * 4] = ev;
    }
    float vv = v[tid];
    v_s[tid] = vv;
    float vp = vv;
#pragma unroll
    for (int m = 1; m < 64; m <<= 1) vp += __shfl_xor(vp, m);
    if ((tid & 63) == 0) red[tid >> 6] = vp;
    __syncthreads();
    float vsum = red[0] + red[1] + red[2] + red[3];
    int tl = tid >> 4, il = tid & 15;
    float acc = 0.f;
#pragma unroll 4
    for (int d = 0; d < 256; ++d) {
        float sval = hp_s[tl][d] + ep_s[il][d];
        float r = frcp(1.0f + fexp2(sval));
        acc = fmaf(v_s[d], r, acc);
    }
    out[((size_t)b * 256 + tt * 16 + tl) * 256 + it * 16 + il] =
        vsum - 2.0f * acc;
}

// ---------------------------------------------------------------------------
extern "C" void kernel_launch(void* const* d_in, const int* in_sizes, int n_in,
                              void* d_out, int out_size, void* d_ws, size_t ws_size,
                              hipStream_t stream)
{
    const float* parts    = (const float*)d_in[0];
    const float* bin_info = (const float*)d_in[1];
    const int*   target   = (const int*)d_in[2];
    const float* pe_W1 = (const float*)d_in[3];
    const float* pe_b1 = (const float*)d_in[4];
    const float* pe_W2 = (const float*)d_in[5];
    const float* pe_b2 = (const float*)d_in[6];
    const float* be_W1 = (const float*)d_in[7];
    const float* be_b1 = (const float*)d_in[8];
    const float* be_W2 = (const float*)d_in[9];
    const float* be_b2 = (const float*)d_in[10];
    const float* pos_emb = (const float*)d_in[11];
    const float* tr_Wqkv = (const float*)d_in[12];
    const float* tr_bqkv = (const float*)d_in[13];
    const float* tr_Wo   = (const float*)d_in[14];
    const float* tr_bo   = (const float*)d_in[15];
    const float* tr_ln1_g = (const float*)d_in[16];
    const float* tr_ln1_b = (const float*)d_in[17];
    const float* tr_ff_W1 = (const float*)d_in[18];
    const float* tr_ff_b1 = (const float*)d_in[19];
    const float* tr_ff_W2 = (const float*)d_in[20];
    const float* tr_ff_b2 = (const float*)d_in[21];
    const float* tr_ln2_g = (const float*)d_in[22];
    const float* tr_ln2_b = (const float*)d_in[23];
    const float* lstm_Wih = (const float*)d_in[24];
    const float* lstm_Whh = (const float*)d_in[25];
    const float* lstm_bih = (const float*)d_in[26];
    const float* lstm_bhh = (const float*)d_in[27];
    const float* ptr_W = (const float*)d_in[28];
    const float* ptr_b = (const float*)d_in[29];
    const float* ptr_v = (const float*)d_in[30];

    // ---- workspace layout (floats) ----
    float* ws = (float*)d_ws;
    float* X     = ws;                        // 2,097,152
    float* S1    = X + 2097152;               // 8,388,608 (qkv/ff1/g_in f16)
    float* CF32  = S1 + 8388608;              // 2,097,152
    float* EPROJ = CF32 + 2097152;            // 2,097,152
    float* X16f  = EPROJ + 2097152;           // 1,048,576
    float* S2f   = X16f + 1048576;            // 1,048,576
    float* W16f  = S2f + 1048576;             // 1,048,576
    float* WBf   = W16f + 1048576;            // 131,072
    float* BBuf  = WBf + 131072;              // 2,048
    float* PB    = BBuf + 2048;               // 1,024

    _Float16* X16    = (_Float16*)X16f;
    _Float16* Xg16   = X16;
    _Float16* S2h    = (_Float16*)S2f;
    _Float16* HALL16 = S2h;
    _Float16* S1h    = (_Float16*)S1;
    _Float16* W16    = (_Float16*)W16f;
    _Float16* Wqkv16 = W16;                   // 589,824
    _Float16* Wo16   = Wqkv16 + 589824;       // 196,608
    _Float16* Wff116 = Wo16 + 196608;         // 393,216
    _Float16* Wff216 = Wff116 + 393216;       // 393,216
    _Float16* Wih16  = Wff216 + 393216;       // 262,144 (gate-interleaved rows)
    _Float16* WpW16  = Wih16 + 262144;        // 65,536

    // ---- one-time weight conversions ----
    cvt_all_kernel<<<7424, 256, 0, stream>>>(tr_Wqkv, tr_Wo, tr_ff_W1, tr_ff_W2,
                                             lstm_Wih, ptr_W, W16);
    wcvt2_kernel<<<512, 256, 0, stream>>>(lstm_Whh, (unsigned int*)WBf,
                                          lstm_bih, lstm_bhh, PB);

    // ---- encoders ----
    bin_enc_kernel<<<32, 64, 0, stream>>>(bin_info, be_W1, be_b1, be_W2, be_b2, BBuf);
    part_enc_kernel<<<256, 128, 0, stream>>>(parts, pe_W1, pe_b1, pe_W2, pe_b2,
                                             BBuf, pos_emb, X, X16);

    // ---- transformer layers ----
    for (int l = 0; l < 3; ++l) {
        hgemm_kernel<64, 128, false, true><<<dim3(128, 6), 256, 0, stream>>>(
            X16, Wqkv16 + (size_t)l * 196608, tr_bqkv + l * 768, nullptr,
            S1h, 8192, 768, 256);
        attn_mfma_kernel<<<256, 256, 0, stream>>>(S1h, S2h);
        hgemm_kernel<64, 64, false, false><<<dim3(128, 4), 256, 0, stream>>>(
            S2h, Wo16 + (size_t)l * 65536, tr_bo + l * 256, nullptr,
            CF32, 8192, 256, 256);
        add_ln_kernel<<<2048, 256, 0, stream>>>(X, CF32, tr_ln1_g + l * 256,
                                                tr_ln1_b + l * 256, X16);
        hgemm_kernel<64, 128, true, true><<<dim3(128, 4), 256, 0, stream>>>(
            X16, Wff116 + (size_t)l * 131072, tr_ff_b1 + l * 512, nullptr,
            S1h, 8192, 512, 256);
        hgemm_kernel<64, 64, false, false><<<dim3(128, 4), 256, 0, stream>>>(
            S1h, Wff216 + (size_t)l * 131072, tr_ff_b2 + l * 256, nullptr,
            CF32, 8192, 256, 512);
        add_ln_kernel<<<2048, 256, 0, stream>>>(X, CF32, tr_ln2_g + l * 256,
                                                tr_ln2_b + l * 256, X16);
    }

    // ---- pointer decode ----
    hgemm_kernel<64, 64, false, false><<<dim3(128, 4), 256, 0, stream>>>(
        X16, WpW16, ptr_b, nullptr, EPROJ, 8192, 256, 256);
    gather_kernel<<<8192, 256, 0, stream>>>(X, target, Xg16);
    hgemm_kernel<64, 128, false, true><<<dim3(128, 8), 256, 0, stream>>>(
        Xg16, Wih16, PB, nullptr, S1h, 8192, 1024, 256);
    lstm_kernel<<<32, 512, 0, stream>>>(S1h, (const uint4*)WBf, HALL16);
    hgemm_kernel<64, 64, false, false><<<dim3(128, 4), 256, 0, stream>>>(
        HALL16, WpW16, ptr_b, nullptr, CF32, 8192, 256, 256);
    pointer_kernel<<<dim3(16, 16, 32), 256, 0, stream>>>(CF32, EPROJ, ptr_v,
                                                         (float*)d_out);
}